// Round 9
// baseline (2361.489 us; speedup 1.0000x reference)
//
#include <hip/hip_runtime.h>

#define DEV __device__ __forceinline__

typedef short bf16x8 __attribute__((ext_vector_type(8)));
typedef float f32x4 __attribute__((ext_vector_type(4)));
typedef int vi4 __attribute__((ext_vector_type(4)));
typedef unsigned uint2v __attribute__((ext_vector_type(2)));
typedef unsigned short u16;
typedef short short4v __attribute__((ext_vector_type(4)));

#define NEGV -1000000000.0f

DEV u16 f2bf(float f) {
  union { float f; unsigned u; } v; v.f = f;
  unsigned r = v.u + 0x7FFFu + ((v.u >> 16) & 1u);
  return (u16)(r >> 16);
}

DEV bf16x8 ld_bf8(const u16* p) {
  vi4 v = *(const vi4*)p;
  return __builtin_bit_cast(bf16x8, v);
}

DEV void gload_lds16(const u16* g, vi4* l) {
  __builtin_amdgcn_global_load_lds((const __attribute__((address_space(1))) void*)g,
                                   (__attribute__((address_space(3))) void*)l, 16, 0, 0);
}

DEV unsigned lds_off(const void* p) {
  return (unsigned)(unsigned long long)(const __attribute__((address_space(3))) void*)p;
}

DEV uint2v ds_tr16(unsigned byteaddr) {
  uint2v r;
  asm volatile("ds_read_b64_tr_b16 %0, %1" : "=v"(r) : "v"(byteaddr));
  return r;
}

// ---------------- generic GEMM: C[M,N] = A[Mpad,K](bf16) @ Bt[N,K](bf16)^T ----------------
// BK=64, 2-buffer pipeline, counted vmcnt. A rows PADDED to mult of 128.
// MODE 0: Cb = bf16(acc+bias); MODE 1: Cf += acc+bias (residual RMW, one writer/elem, KS=1);
// MODE 2: Cf = acc (+bias); MODE 3: patch-embed scatter with pos_embed.
template<int BN, int MODE, bool GELU, int KS>
__global__ __launch_bounds__(256) void gemm_bt(
    const u16* __restrict__ A, const u16* __restrict__ Bt,
    const float* __restrict__ bias,
    float* __restrict__ Cf, u16* __restrict__ Cb,
    int M, int N, int K, const float* __restrict__ pos)
{
  constexpr int FJ = BN / 32;
  constexpr int LTOT = 4 + FJ;
  __shared__ vi4 As[2][1024];
  __shared__ vi4 Bs[2][BN * 8];

  // bijective XCD-aware swizzle (m204)
  int gx = gridDim.x, gy = gridDim.y;
  int nwg = gx * gy * (int)gridDim.z;
  int orig = blockIdx.x + gx * (blockIdx.y + gy * blockIdx.z);
  int qq = nwg >> 3, rr = nwg & 7;
  int xcd = orig & 7, off = orig >> 3;
  int id = (xcd < rr) ? xcd * (qq + 1) + off : rr * (qq + 1) + (xcd - rr) * qq + off;
  int bx = id % gx, rest = id / gx, by = rest % gy, bz = rest / gy;

  int tid = threadIdx.x, lane = tid & 63, wid = tid >> 6;
  int wm = wid >> 1, wn = wid & 1;
  int m0 = by * 128, n0 = bx * BN;
  int kBeg = (K / KS) * bz;
  int nT = (K / KS) >> 6;
  f32x4 acc[4][FJ] = {};

  auto STAGE = [&](int buf, int kk) {
    #pragma unroll
    for (int r = 0; r < 4; ++r) {
      int flat = r * 256 + tid;
      int row = flat >> 3, c = flat & 7;
      int cs = c ^ (row & 7);
      gload_lds16(A + (long)(m0 + row) * K + kk + cs * 8, &As[buf][r * 256 + wid * 64]);
    }
    #pragma unroll
    for (int r = 0; r < FJ; ++r) {
      int flat = r * 256 + tid;
      int row = flat >> 3, c = flat & 7;
      int cs = c ^ (row & 7);
      gload_lds16(Bt + (long)(n0 + row) * K + kk + cs * 8, &Bs[buf][r * 256 + wid * 64]);
    }
  };

  STAGE(0, kBeg);
  int cur = 0;
  for (int t = 0; t < nT; ++t) {
    if (t + 1 < nT) {
      STAGE(cur ^ 1, kBeg + (t + 1) * 64);
      asm volatile("s_waitcnt vmcnt(%0)" :: "i"(LTOT) : "memory");
    } else {
      asm volatile("s_waitcnt vmcnt(0)" ::: "memory");
    }
    __builtin_amdgcn_s_barrier();
    int cg = lane >> 4, l15 = lane & 15;
    #pragma unroll
    for (int ks = 0; ks < 2; ++ks) {
      bf16x8 af[4], bfr[FJ];
      #pragma unroll
      for (int i = 0; i < 4; ++i) {
        int ra = wm * 64 + i * 16 + l15;
        af[i] = __builtin_bit_cast(bf16x8, As[cur][ra * 8 + ((ks * 4 + cg) ^ (ra & 7))]);
      }
      #pragma unroll
      for (int j = 0; j < FJ; ++j) {
        int rb = wn * (BN / 2) + j * 16 + l15;
        bfr[j] = __builtin_bit_cast(bf16x8, Bs[cur][rb * 8 + ((ks * 4 + cg) ^ (rb & 7))]);
      }
      #pragma unroll
      for (int i = 0; i < 4; ++i)
        #pragma unroll
        for (int j = 0; j < FJ; ++j)
          acc[i][j] = __builtin_amdgcn_mfma_f32_16x16x32_bf16(af[i], bfr[j], acc[i][j], 0, 0, 0);
    }
    __builtin_amdgcn_s_barrier();
    cur ^= 1;
  }

  int cg = lane >> 4, l15 = lane & 15;
  #pragma unroll
  for (int i = 0; i < 4; ++i) {
    #pragma unroll
    for (int j = 0; j < FJ; ++j) {
      int col = n0 + wn * (BN / 2) + j * 16 + l15;
      float bv = bias ? bias[col] : 0.f;
      #pragma unroll
      for (int r = 0; r < 4; ++r) {
        int row = m0 + wm * 64 + i * 16 + cg * 4 + r;
        if (row < M) {
          float v = acc[i][j][r] + bv;
          if (GELU) v = v / (1.f + __expf(-1.702f * v));
          if (MODE == 0) Cb[(long)row * N + col] = f2bf(v);
          else if (MODE == 1) Cf[(long)row * N + col] += v;
          else if (MODE == 2) Cf[(long)row * N + col] = v;
          else {
            int hw = row % 196;
            int xr = (row / 196) * 223 + 27 + hw;
            Cf[(long)xr * 768 + col] = v + pos[(27 + hw) * 768 + col];
          }
        }
      }
    }
  }
}

// ---------------- attention (swapped QK^T, in-register P, tr_b16 V reads) ----------------
__global__ __launch_bounds__(256) void attn_kernel(
    const u16* __restrict__ QKV, const int* __restrict__ aom, u16* __restrict__ O)
{
  __shared__ vi4 Kl[224 * 8];   // K row-major [key][8 chunks], chunk XOR (key&7)
  __shared__ vi4 Vl[224 * 8];   // V subtiled [sk][sd^(sk&3)][4 keys][16 d] (128B subtiles)
  __shared__ int ml[196];
  int tid = threadIdx.x, lane = tid & 63, wid = tid >> 6;
  int qg = blockIdx.x, h = blockIdx.y, b = blockIdx.z;
  long rowbase = (long)b * 223;
  #pragma unroll
  for (int it = 0; it < 7; ++it) {
    int flat = it * 256 + tid;
    int s = flat >> 3, c = flat & 7;
    int cs = c ^ (s & 7);
    gload_lds16(QKV + (rowbase + s) * 2304 + 768 + h * 64 + cs * 8, &Kl[it * 256 + wid * 64]);
  }
  #pragma unroll
  for (int it = 0; it < 7; ++it) {
    int u = it * 256 + tid;
    int slin = u >> 3, inner = u & 7;
    int sk = slin >> 2, sdp = slin & 3;
    int s = sk * 4 + (inner >> 1);
    int c = ((sdp ^ (sk & 3)) << 1) | (inner & 1);
    gload_lds16(QKV + (rowbase + s) * 2304 + 1536 + h * 64 + c * 8, &Vl[it * 256 + wid * 64]);
  }
  for (int i = tid; i < 196; i += 256) ml[i] = aom[b * 196 + i];
  __syncthreads();

  int l15 = lane & 15, cg = lane >> 4;
  unsigned vbase = lds_off(Vl);
  #pragma unroll
  for (int rep = 0; rep < 2; ++rep) {
    int fo = wid * 2 + rep;
    if (fo >= 7) break;
    int qf = qg * 7 + fo;
    int q0 = qf * 16;
    int arow = q0 + l15; if (arow > 222) arow = 222;
    const u16* qb = QKV + (rowbase + arow) * 2304 + h * 64;
    bf16x8 aq0 = ld_bf8(qb + cg * 8);
    bf16x8 aq1 = ld_bf8(qb + 32 + cg * 8);

    f32x4 sc[14];
    #pragma unroll
    for (int kf = 0; kf < 14; ++kf) {
      int key = kf * 16 + l15;
      f32x4 a = {0.f, 0.f, 0.f, 0.f};
      bf16x8 bk0 = __builtin_bit_cast(bf16x8, Kl[key * 8 + (cg ^ (key & 7))]);
      bf16x8 bk1 = __builtin_bit_cast(bf16x8, Kl[key * 8 + ((4 + cg) ^ (key & 7))]);
      a = __builtin_amdgcn_mfma_f32_16x16x32_bf16(bk0, aq0, a, 0, 0, 0);
      a = __builtin_amdgcn_mfma_f32_16x16x32_bf16(bk1, aq1, a, 0, 0, 0);
      sc[kf] = a;
    }
    int q = q0 + l15;
    float mx = -3.4e38f;
    #pragma unroll
    for (int kf = 0; kf < 14; ++kf) {
      #pragma unroll
      for (int r = 0; r < 4; ++r) {
        int key = kf * 16 + cg * 4 + r;
        float mval;
        if (key >= 223) mval = NEGV;
        else if (q >= 27) mval = (key < 27) ? NEGV : 0.f;
        else if (key < 27) mval = (key == q) ? 0.f : NEGV;
        else mval = (ml[key - 27] == q) ? 0.f : NEGV;
        float sv = sc[kf][r] * 0.125f + mval;
        sc[kf][r] = sv;
        mx = fmaxf(mx, sv);
      }
    }
    mx = fmaxf(mx, __shfl_xor(mx, 16));
    mx = fmaxf(mx, __shfl_xor(mx, 32));
    float sum = 0.f;
    #pragma unroll
    for (int kf = 0; kf < 14; ++kf) {
      #pragma unroll
      for (int r = 0; r < 4; ++r) {
        float e = __expf(sc[kf][r] - mx);
        sc[kf][r] = e; sum += e;
      }
    }
    sum += __shfl_xor(sum, 16);
    sum += __shfl_xor(sum, 32);
    float inv = 1.f / sum;
    unsigned plo[14], phi[14];
    #pragma unroll
    for (int kf = 0; kf < 14; ++kf) {
      plo[kf] = (unsigned)f2bf(sc[kf][0] * inv) | ((unsigned)f2bf(sc[kf][1] * inv) << 16);
      phi[kf] = (unsigned)f2bf(sc[kf][2] * inv) | ((unsigned)f2bf(sc[kf][3] * inv) << 16);
    }
    f32x4 oacc[4] = {};
    #pragma unroll
    for (int ks = 0; ks < 7; ++ks) {
      uint2v vr[4][2];
      int sk0 = ks * 8 + cg * 2, sk1 = sk0 + 1;
      #pragma unroll
      for (int nf = 0; nf < 4; ++nf) {
        vr[nf][0] = ds_tr16(vbase + (unsigned)(((sk0 * 4 + (nf ^ (sk0 & 3))) << 7) + l15 * 8));
        vr[nf][1] = ds_tr16(vbase + (unsigned)(((sk1 * 4 + (nf ^ (sk1 & 3))) << 7) + l15 * 8));
      }
      int src0 = ((cg & 1) << 5) + l15, src1 = src0 + 16;
      int lo0 = __shfl((int)plo[2 * ks], src0),     hi0 = __shfl((int)phi[2 * ks], src0);
      int lo1 = __shfl((int)plo[2 * ks + 1], src0), hi1 = __shfl((int)phi[2 * ks + 1], src0);
      int lo0b = __shfl((int)plo[2 * ks], src1),     hi0b = __shfl((int)phi[2 * ks], src1);
      int lo1b = __shfl((int)plo[2 * ks + 1], src1), hi1b = __shfl((int)phi[2 * ks + 1], src1);
      bool hg = (cg >> 1) & 1;
      vi4 paw = { hg ? lo1 : lo0, hg ? hi1 : hi0, hg ? lo1b : lo0b, hg ? hi1b : hi0b };
      bf16x8 pa = __builtin_bit_cast(bf16x8, paw);
      asm volatile("s_waitcnt lgkmcnt(0)" ::: "memory");
      __builtin_amdgcn_sched_barrier(0);
      #pragma unroll
      for (int nf = 0; nf < 4; ++nf) {
        vi4 bw = { (int)vr[nf][0][0], (int)vr[nf][0][1], (int)vr[nf][1][0], (int)vr[nf][1][1] };
        oacc[nf] = __builtin_amdgcn_mfma_f32_16x16x32_bf16(pa, __builtin_bit_cast(bf16x8, bw), oacc[nf], 0, 0, 0);
      }
    }
    #pragma unroll
    for (int nf = 0; nf < 4; ++nf) {
      int d = h * 64 + nf * 16 + l15;
      #pragma unroll
      for (int r = 0; r < 4; ++r) {
        int qo = q0 + cg * 4 + r;
        if (qo < 223) O[(rowbase + qo) * 768 + d] = f2bf(oacc[nf][r]);
      }
    }
  }
}

// ---------------- LayerNorm: one WAVE per row, read x -> write H ----------------
template<bool MAP27>
__global__ __launch_bounds__(256) void ln_kernel(
    const float* __restrict__ X, u16* __restrict__ Hb,
    const float* __restrict__ w, const float* __restrict__ bb, int nrows)
{
  int row = blockIdx.x * 4 + (threadIdx.x >> 6);
  if (row >= nrows) return;
  int xr = MAP27 ? (row / 27) * 223 + (row % 27) : row;
  int l = threadIdx.x & 63;
  const float4* xp = (const float4*)(X + (long)xr * 768);
  float4 a = xp[l], c = xp[l + 64], d = xp[l + 128];
  float s = a.x + a.y + a.z + a.w + c.x + c.y + c.z + c.w + d.x + d.y + d.z + d.w;
  #pragma unroll
  for (int t = 1; t < 64; t <<= 1) s += __shfl_xor(s, t);
  float mean = s * (1.f / 768.f);
  a.x -= mean; a.y -= mean; a.z -= mean; a.w -= mean;
  c.x -= mean; c.y -= mean; c.z -= mean; c.w -= mean;
  d.x -= mean; d.y -= mean; d.z -= mean; d.w -= mean;
  float q = a.x*a.x + a.y*a.y + a.z*a.z + a.w*a.w
          + c.x*c.x + c.y*c.y + c.z*c.z + c.w*c.w
          + d.x*d.x + d.y*d.y + d.z*d.z + d.w*d.w;
  #pragma unroll
  for (int t = 1; t < 64; t <<= 1) q += __shfl_xor(q, t);
  float rs = rsqrtf(q * (1.f / 768.f) + 1e-5f);
  const float4* wp = (const float4*)w;
  const float4* bp = (const float4*)bb;
  u16* out = Hb + (long)row * 768;
  float4 w0 = wp[l], w1 = wp[l + 64], w2 = wp[l + 128];
  float4 b0 = bp[l], b1 = bp[l + 64], b2 = bp[l + 128];
  short4v o;
  o[0] = (short)f2bf(a.x * rs * w0.x + b0.x); o[1] = (short)f2bf(a.y * rs * w0.y + b0.y);
  o[2] = (short)f2bf(a.z * rs * w0.z + b0.z); o[3] = (short)f2bf(a.w * rs * w0.w + b0.w);
  *(short4v*)(out + l * 4) = o;
  o[0] = (short)f2bf(c.x * rs * w1.x + b1.x); o[1] = (short)f2bf(c.y * rs * w1.y + b1.y);
  o[2] = (short)f2bf(c.z * rs * w1.z + b1.z); o[3] = (short)f2bf(c.w * rs * w1.w + b1.w);
  *(short4v*)(out + 256 + l * 4) = o;
  o[0] = (short)f2bf(d.x * rs * w2.x + b2.x); o[1] = (short)f2bf(d.y * rs * w2.y + b2.y);
  o[2] = (short)f2bf(d.z * rs * w2.z + b2.z); o[3] = (short)f2bf(d.w * rs * w2.w + b2.w);
  *(short4v*)(out + 512 + l * 4) = o;
}

// ---------------- weight transpose + f32->bf16: W[K][N] -> WT[N][K], batched over z ----------------
__global__ __launch_bounds__(256) void transpose_w(
    const float* __restrict__ W, u16* __restrict__ WT, int K, int N, long sW, long sT)
{
  __shared__ float t[64][65];
  int z = blockIdx.z;
  W += (long)z * sW; WT += (long)z * sT;
  int n0 = blockIdx.x * 64, k0 = blockIdx.y * 64;
  #pragma unroll
  for (int i = 0; i < 4; ++i) {
    int flat = i * 256 + threadIdx.x;
    int r = flat >> 4, c = (flat & 15) * 4;
    float4 v = *(const float4*)(W + (long)(k0 + r) * N + n0 + c);
    t[r][c] = v.x; t[r][c + 1] = v.y; t[r][c + 2] = v.z; t[r][c + 3] = v.w;
  }
  __syncthreads();
  #pragma unroll
  for (int i = 0; i < 8; ++i) {
    int flat = i * 256 + threadIdx.x;
    int rn = flat >> 5, ck = (flat & 31) * 2;
    unsigned val = (unsigned)f2bf(t[ck][rn]) | ((unsigned)f2bf(t[ck + 1][rn]) << 16);
    *(unsigned*)(WT + (long)(n0 + rn) * K + k0 + ck) = val;
  }
}

__global__ void convert_bf16(const float* __restrict__ src, u16* __restrict__ dst, int n) {
  int i = blockIdx.x * 256 + threadIdx.x;
  if (i < n) dst[i] = f2bf(src[i]);
}

__global__ __launch_bounds__(192) void patch_extract(const float* __restrict__ img, u16* __restrict__ Xp) {
  int row = blockIdx.x;
  int t = threadIdx.x;
  int pair = t >> 2, part = t & 3;
  int cch = pair >> 4, kh = pair & 15;
  int b = row / 196, hw = row % 196, gh = hw / 14, gw = hw % 14;
  float4 v = *(const float4*)(img + ((long)(b * 3 + cch) * 224 + gh * 16 + kh) * 224 + gw * 16 + part * 4);
  short4v o;
  o[0] = (short)f2bf(v.x); o[1] = (short)f2bf(v.y); o[2] = (short)f2bf(v.z); o[3] = (short)f2bf(v.w);
  *(short4v*)(Xp + (long)row * 768 + pair * 16 + part * 4) = o;
}

__global__ void cls_pos_fill(const float* __restrict__ cls, const float* __restrict__ pos, float* __restrict__ x) {
  int i = blockIdx.x * 256 + threadIdx.x;
  if (i >= 16 * 27 * 768) return;
  int d = i % 768, t = i / 768, b = t / 27, s = t % 27;
  x[((long)b * 223 + s) * 768 + d] = cls[s * 768 + d] + pos[s * 768 + d];
}

__global__ __launch_bounds__(256) void sents_norm(const float* __restrict__ s, float* __restrict__ sn) {
  __shared__ float sb[4];
  int b = blockIdx.x, t = threadIdx.x;
  float v0 = s[b * 512 + t], v1 = s[b * 512 + t + 256];
  float q = v0 * v0 + v1 * v1;
  #pragma unroll
  for (int d = 1; d < 64; d <<= 1) q += __shfl_xor(q, d);
  if ((t & 63) == 0) sb[t >> 6] = q;
  __syncthreads();
  float inv = rsqrtf(sb[0] + sb[1] + sb[2] + sb[3]);
  sn[b * 512 + t] = v0 * inv;
  sn[b * 512 + t + 256] = v1 * inv;
}

__global__ __launch_bounds__(256) void obj_dot(const float* __restrict__ obj, const float* __restrict__ sn, float* __restrict__ pid) {
  __shared__ float sb[8];
  int r = blockIdx.x, t = threadIdx.x, b = r / 27;
  float v0 = obj[(long)r * 512 + t], v1 = obj[(long)r * 512 + t + 256];
  float w0 = sn[b * 512 + t], w1 = sn[b * 512 + t + 256];
  float q = v0 * v0 + v1 * v1;
  float dt = v0 * w0 + v1 * w1;
  #pragma unroll
  for (int d = 1; d < 64; d <<= 1) { q += __shfl_xor(q, d); dt += __shfl_xor(dt, d); }
  if ((t & 63) == 0) { sb[t >> 6] = q; sb[4 + (t >> 6)] = dt; }
  __syncthreads();
  if (t == 0) pid[r] = (sb[4] + sb[5] + sb[6] + sb[7]) * rsqrtf(sb[0] + sb[1] + sb[2] + sb[3]);
}

__global__ void gather_pred(const int* __restrict__ om, const float* __restrict__ pid, float* __restrict__ out) {
  int i = blockIdx.x * 256 + threadIdx.x;
  if (i >= 16 * 224 * 224) return;
  int b = i / (224 * 224);
  out[i] = pid[b * 27 + om[i]];
}

extern "C" void kernel_launch(void* const* d_in, const int* in_sizes, int n_in,
                              void* d_out, int out_size, void* d_ws, size_t ws_size,
                              hipStream_t stream) {
  const float* img     = (const float*)d_in[0];
  const float* sents   = (const float*)d_in[1];
  const int*   aom     = (const int*)d_in[2];
  const int*   omask   = (const int*)d_in[3];
  const float* cls     = (const float*)d_in[4];
  const float* patch_w = (const float*)d_in[5];
  const float* patch_b = (const float*)d_in[6];
  const float* pos     = (const float*)d_in[7];
  const float* ln1w    = (const float*)d_in[8];
  const float* ln1b    = (const float*)d_in[9];
  const float* qkvw    = (const float*)d_in[10];
  const float* qkvb    = (const float*)d_in[11];
  const float* outw    = (const float*)d_in[12];
  const float* outb    = (const float*)d_in[13];
  const float* ln2w    = (const float*)d_in[14];
  const float* ln2b    = (const float*)d_in[15];
  const float* m1w     = (const float*)d_in[16];
  const float* m1b     = (const float*)d_in[17];
  const float* m2w     = (const float*)d_in[18];
  const float* m2b     = (const float*)d_in[19];
  const float* lnpw    = (const float*)d_in[20];
  const float* lnpb    = (const float*)d_in[21];
  const float* projw   = (const float*)d_in[22];

  char* p = (char*)d_ws;
  auto alloc = [&](size_t bytes) { char* r = p; p += (bytes + 255) & ~(size_t)255; return r; };
  float* x   = (float*)alloc(3568ul * 768 * 4);
  u16* H     = (u16*)alloc(3584ul * 768 * 2);
  u16* QKV   = (u16*)alloc(3584ul * 2304 * 2);
  u16* Obuf  = (u16*)alloc(3584ul * 768 * 2);
  u16* G     = (u16*)alloc(3584ul * 3072 * 2);
  u16* PWc   = (u16*)alloc(768ul * 768 * 2);
  u16* PrT   = (u16*)alloc(512ul * 768 * 2);
  float* obj = (float*)alloc(432ul * 512 * 4);
  float* sn  = (float*)alloc(16ul * 512 * 4);
  float* pid = (float*)alloc(432ul * 4);

  const size_t wlayer = (2304ul * 768 + 768ul * 768 + 3072ul * 768 + 768ul * 3072) * 2;
  size_t used = (size_t)(p - (char*)d_ws);
  int nw = (ws_size >= used + 12 * wlayer + 65536) ? 12 : 1;
  const long sQ = 2304l * 768, sO = 768l * 768, s1 = 768l * 3072, s2 = 3072l * 768;
  u16* WqT = (u16*)alloc((size_t)sQ * 2 * nw);
  u16* WoT = (u16*)alloc((size_t)sO * 2 * nw);
  u16* W1T = (u16*)alloc((size_t)s1 * 2 * nw);
  u16* W2T = (u16*)alloc((size_t)s2 * 2 * nw);

  convert_bf16<<<2304, 256, 0, stream>>>(patch_w, PWc, 768 * 768);
  transpose_w<<<dim3(8, 12, 1), 256, 0, stream>>>(projw, PrT, 768, 512, 0, 0);
  if (nw == 12) {
    transpose_w<<<dim3(36, 12, 12), 256, 0, stream>>>(qkvw, WqT, 768, 2304, sQ, sQ);
    transpose_w<<<dim3(12, 12, 12), 256, 0, stream>>>(outw, WoT, 768, 768, sO, sO);
    transpose_w<<<dim3(48, 12, 12), 256, 0, stream>>>(m1w, W1T, 768, 3072, s1, s1);
    transpose_w<<<dim3(12, 48, 12), 256, 0, stream>>>(m2w, W2T, 3072, 768, s2, s2);
  }
  patch_extract<<<3136, 192, 0, stream>>>(img, H);
  cls_pos_fill<<<1296, 256, 0, stream>>>(cls, pos, x);
  gemm_bt<64, 3, false, 1><<<dim3(12, 25), 256, 0, stream>>>(H, PWc, patch_b, x, nullptr, 3136, 768, 768, pos);

  for (int l = 0; l < 12; ++l) {
    u16 *wq, *wo, *w1, *w2;
    if (nw == 12) { wq = WqT + (long)l * sQ; wo = WoT + (long)l * sO; w1 = W1T + (long)l * s1; w2 = W2T + (long)l * s2; }
    else {
      wq = WqT; wo = WoT; w1 = W1T; w2 = W2T;
      transpose_w<<<dim3(36, 12, 1), 256, 0, stream>>>(qkvw + (long)l * sQ, wq, 768, 2304, 0, 0);
      transpose_w<<<dim3(12, 12, 1), 256, 0, stream>>>(outw + (long)l * sO, wo, 768, 768, 0, 0);
      transpose_w<<<dim3(48, 12, 1), 256, 0, stream>>>(m1w + (long)l * s1, w1, 768, 3072, 0, 0);
      transpose_w<<<dim3(12, 48, 1), 256, 0, stream>>>(m2w + (long)l * s2, w2, 3072, 768, 0, 0);
    }
    ln_kernel<false><<<892, 256, 0, stream>>>(x, H, ln1w + l * 768, ln1b + l * 768, 3568);
    gemm_bt<128, 0, false, 1><<<dim3(18, 28), 256, 0, stream>>>(H, wq, qkvb + l * 2304, nullptr, QKV, 3568, 2304, 768, nullptr);
    attn_kernel<<<dim3(2, 12, 16), 256, 0, stream>>>(QKV, aom, Obuf);
    gemm_bt<64, 1, false, 1><<<dim3(12, 28), 256, 0, stream>>>(Obuf, wo, outb + l * 768, x, nullptr, 3568, 768, 768, nullptr);
    ln_kernel<false><<<892, 256, 0, stream>>>(x, H, ln2w + l * 768, ln2b + l * 768, 3568);
    gemm_bt<128, 0, true, 1><<<dim3(24, 28), 256, 0, stream>>>(H, w1, m1b + l * 3072, nullptr, G, 3568, 3072, 768, nullptr);
    gemm_bt<64, 1, false, 1><<<dim3(12, 28), 256, 0, stream>>>(G, w2, m2b + l * 768, x, nullptr, 3568, 768, 3072, nullptr);
  }

  ln_kernel<true><<<108, 256, 0, stream>>>(x, H, lnpw, lnpb, 432);
  gemm_bt<64, 2, false, 1><<<dim3(8, 4), 256, 0, stream>>>(H, PrT, nullptr, obj, nullptr, 432, 512, 768, nullptr);
  sents_norm<<<16, 256, 0, stream>>>(sents, sn);
  obj_dot<<<432, 256, 0, stream>>>(obj, sn, pid);
  gather_pred<<<3136, 256, 0, stream>>>(omask, pid, (float*)d_out);
}

// Round 10
// 2139.052 us; speedup vs baseline: 1.1040x; 1.1040x over previous
//
#include <hip/hip_runtime.h>

#define DEV __device__ __forceinline__

typedef short bf16x8 __attribute__((ext_vector_type(8)));
typedef float f32x4 __attribute__((ext_vector_type(4)));
typedef int vi4 __attribute__((ext_vector_type(4)));
typedef unsigned uint2v __attribute__((ext_vector_type(2)));
typedef unsigned short u16;
typedef short short4v __attribute__((ext_vector_type(4)));

#define NEGV -1000000000.0f

DEV u16 f2bf(float f) {
  union { float f; unsigned u; } v; v.f = f;
  unsigned r = v.u + 0x7FFFu + ((v.u >> 16) & 1u);
  return (u16)(r >> 16);
}

DEV bf16x8 ld_bf8(const u16* p) {
  vi4 v = *(const vi4*)p;
  return __builtin_bit_cast(bf16x8, v);
}

DEV void gload_lds16(const u16* g, vi4* l) {
  __builtin_amdgcn_global_load_lds((const __attribute__((address_space(1))) void*)g,
                                   (__attribute__((address_space(3))) void*)l, 16, 0, 0);
}

DEV unsigned lds_off(const void* p) {
  return (unsigned)(unsigned long long)(const __attribute__((address_space(3))) void*)p;
}

DEV uint2v ds_tr16(unsigned byteaddr) {
  uint2v r;
  asm volatile("ds_read_b64_tr_b16 %0, %1" : "=v"(r) : "v"(byteaddr));
  return r;
}

// ---------------- generic GEMM: C[M,N] = A[Mpad,K](bf16) @ Bt[N,K](bf16)^T ----------------
// BK=64, 2-buffer pipeline, counted vmcnt. A rows PADDED to mult of 128.
// MODE 0: Cb = bf16(acc+bias); MODE 2: Cf[+bz*pstride] = acc (+bias@z0) — split-K partials,
// no atomics (summed by following fused-LN kernel); MODE 3: patch-embed scatter.
template<int BN, int MODE, bool GELU, int KS>
__global__ __launch_bounds__(256) void gemm_bt(
    const u16* __restrict__ A, const u16* __restrict__ Bt,
    const float* __restrict__ bias,
    float* __restrict__ Cf, u16* __restrict__ Cb,
    int M, int N, int K, const float* __restrict__ pos, long pstride)
{
  constexpr int FJ = BN / 32;
  constexpr int LTOT = 4 + FJ;
  __shared__ vi4 As[2][1024];
  __shared__ vi4 Bs[2][BN * 8];

  // bijective XCD-aware swizzle (m204)
  int gx = gridDim.x, gy = gridDim.y;
  int nwg = gx * gy * (int)gridDim.z;
  int orig = blockIdx.x + gx * (blockIdx.y + gy * blockIdx.z);
  int qq = nwg >> 3, rr = nwg & 7;
  int xcd = orig & 7, off = orig >> 3;
  int id = (xcd < rr) ? xcd * (qq + 1) + off : rr * (qq + 1) + (xcd - rr) * qq + off;
  int bx = id % gx, rest = id / gx, by = rest % gy, bz = rest / gy;

  int tid = threadIdx.x, lane = tid & 63, wid = tid >> 6;
  int wm = wid >> 1, wn = wid & 1;
  int m0 = by * 128, n0 = bx * BN;
  int kBeg = (K / KS) * bz;
  int nT = (K / KS) >> 6;
  f32x4 acc[4][FJ] = {};

  auto STAGE = [&](int buf, int kk) {
    #pragma unroll
    for (int r = 0; r < 4; ++r) {
      int flat = r * 256 + tid;
      int row = flat >> 3, c = flat & 7;
      int cs = c ^ (row & 7);
      gload_lds16(A + (long)(m0 + row) * K + kk + cs * 8, &As[buf][r * 256 + wid * 64]);
    }
    #pragma unroll
    for (int r = 0; r < FJ; ++r) {
      int flat = r * 256 + tid;
      int row = flat >> 3, c = flat & 7;
      int cs = c ^ (row & 7);
      gload_lds16(Bt + (long)(n0 + row) * K + kk + cs * 8, &Bs[buf][r * 256 + wid * 64]);
    }
  };

  STAGE(0, kBeg);
  int cur = 0;
  for (int t = 0; t < nT; ++t) {
    if (t + 1 < nT) {
      STAGE(cur ^ 1, kBeg + (t + 1) * 64);
      asm volatile("s_waitcnt vmcnt(%0)" :: "i"(LTOT) : "memory");
    } else {
      asm volatile("s_waitcnt vmcnt(0)" ::: "memory");
    }
    __builtin_amdgcn_s_barrier();
    int cg = lane >> 4, l15 = lane & 15;
    #pragma unroll
    for (int ks = 0; ks < 2; ++ks) {
      bf16x8 af[4], bfr[FJ];
      #pragma unroll
      for (int i = 0; i < 4; ++i) {
        int ra = wm * 64 + i * 16 + l15;
        af[i] = __builtin_bit_cast(bf16x8, As[cur][ra * 8 + ((ks * 4 + cg) ^ (ra & 7))]);
      }
      #pragma unroll
      for (int j = 0; j < FJ; ++j) {
        int rb = wn * (BN / 2) + j * 16 + l15;
        bfr[j] = __builtin_bit_cast(bf16x8, Bs[cur][rb * 8 + ((ks * 4 + cg) ^ (rb & 7))]);
      }
      #pragma unroll
      for (int i = 0; i < 4; ++i)
        #pragma unroll
        for (int j = 0; j < FJ; ++j)
          acc[i][j] = __builtin_amdgcn_mfma_f32_16x16x32_bf16(af[i], bfr[j], acc[i][j], 0, 0, 0);
    }
    __builtin_amdgcn_s_barrier();
    cur ^= 1;
  }

  int cg = lane >> 4, l15 = lane & 15;
  float* Cfz = (MODE == 2 && KS > 1) ? Cf + (long)bz * pstride : Cf;
  #pragma unroll
  for (int i = 0; i < 4; ++i) {
    #pragma unroll
    for (int j = 0; j < FJ; ++j) {
      int col = n0 + wn * (BN / 2) + j * 16 + l15;
      float bv = bias ? bias[col] : 0.f;
      #pragma unroll
      for (int r = 0; r < 4; ++r) {
        int row = m0 + wm * 64 + i * 16 + cg * 4 + r;
        if (row < M) {
          float v = acc[i][j][r];
          if (KS == 1 || bz == 0) v += bv;
          if (GELU) v = v / (1.f + __expf(-1.702f * v));
          if (MODE == 0) Cb[(long)row * N + col] = f2bf(v);
          else if (MODE == 2) Cfz[(long)row * N + col] = v;
          else {
            int hw = row % 196;
            int xr = (row / 196) * 223 + 27 + hw;
            Cf[(long)xr * 768 + col] = v + pos[(27 + hw) * 768 + col];
          }
        }
      }
    }
  }
}

// ---------------- attention (swapped QK^T, in-register P, tr_b16 V reads) ----------------
// grid (2 qhalves, 12 heads, 16 batch); block 256. XCD-pair swizzle: both qg of one (h,b)
// land on the same XCD so the second block's K/V reads hit L2.
__global__ __launch_bounds__(256) void attn_kernel(
    const u16* __restrict__ QKV, const int* __restrict__ aom, u16* __restrict__ O)
{
  __shared__ vi4 Kl[224 * 8];   // K row-major [key][8 chunks], chunk XOR (key&7)
  __shared__ vi4 Vl[224 * 8];   // V subtiled [sk][sd^(sk&3)][4 keys][16 d] (128B subtiles)
  __shared__ int ml[196];
  int tid = threadIdx.x, lane = tid & 63, wid = tid >> 6;
  // m204 swizzle, nwg = 384 (384 % 8 == 0): id = (orig&7)*48 + orig>>3
  int orig = blockIdx.x + 2 * (blockIdx.y + 12 * blockIdx.z);
  int id = (orig & 7) * 48 + (orig >> 3);
  int qg = id & 1, h = (id >> 1) % 12, b = id / 24;
  long rowbase = (long)b * 223;
  #pragma unroll
  for (int it = 0; it < 7; ++it) {
    int flat = it * 256 + tid;
    int s = flat >> 3, c = flat & 7;
    int cs = c ^ (s & 7);
    gload_lds16(QKV + (rowbase + s) * 2304 + 768 + h * 64 + cs * 8, &Kl[it * 256 + wid * 64]);
  }
  #pragma unroll
  for (int it = 0; it < 7; ++it) {
    int u = it * 256 + tid;
    int slin = u >> 3, inner = u & 7;
    int sk = slin >> 2, sdp = slin & 3;
    int s = sk * 4 + (inner >> 1);
    int c = ((sdp ^ (sk & 3)) << 1) | (inner & 1);
    gload_lds16(QKV + (rowbase + s) * 2304 + 1536 + h * 64 + c * 8, &Vl[it * 256 + wid * 64]);
  }
  for (int i = tid; i < 196; i += 256) ml[i] = aom[b * 196 + i];
  __syncthreads();

  int l15 = lane & 15, cg = lane >> 4;
  unsigned vbase = lds_off(Vl);
  #pragma unroll
  for (int rep = 0; rep < 2; ++rep) {
    int fo = wid * 2 + rep;
    if (fo >= 7) break;
    int qf = qg * 7 + fo;
    int q0 = qf * 16;
    int arow = q0 + l15; if (arow > 222) arow = 222;
    const u16* qb = QKV + (rowbase + arow) * 2304 + h * 64;
    bf16x8 aq0 = ld_bf8(qb + cg * 8);
    bf16x8 aq1 = ld_bf8(qb + 32 + cg * 8);

    f32x4 sc[14];
    #pragma unroll
    for (int kf = 0; kf < 14; ++kf) {
      int key = kf * 16 + l15;
      f32x4 a = {0.f, 0.f, 0.f, 0.f};
      bf16x8 bk0 = __builtin_bit_cast(bf16x8, Kl[key * 8 + (cg ^ (key & 7))]);
      bf16x8 bk1 = __builtin_bit_cast(bf16x8, Kl[key * 8 + ((4 + cg) ^ (key & 7))]);
      a = __builtin_amdgcn_mfma_f32_16x16x32_bf16(bk0, aq0, a, 0, 0, 0);
      a = __builtin_amdgcn_mfma_f32_16x16x32_bf16(bk1, aq1, a, 0, 0, 0);
      sc[kf] = a;
    }
    int q = q0 + l15;
    float mx = -3.4e38f;
    #pragma unroll
    for (int kf = 0; kf < 14; ++kf) {
      #pragma unroll
      for (int r = 0; r < 4; ++r) {
        int key = kf * 16 + cg * 4 + r;
        float mval;
        if (key >= 223) mval = NEGV;
        else if (q >= 27) mval = (key < 27) ? NEGV : 0.f;
        else if (key < 27) mval = (key == q) ? 0.f : NEGV;
        else mval = (ml[key - 27] == q) ? 0.f : NEGV;
        float sv = sc[kf][r] * 0.125f + mval;
        sc[kf][r] = sv;
        mx = fmaxf(mx, sv);
      }
    }
    mx = fmaxf(mx, __shfl_xor(mx, 16));
    mx = fmaxf(mx, __shfl_xor(mx, 32));
    float sum = 0.f;
    #pragma unroll
    for (int kf = 0; kf < 14; ++kf) {
      #pragma unroll
      for (int r = 0; r < 4; ++r) {
        float e = __expf(sc[kf][r] - mx);
        sc[kf][r] = e; sum += e;
      }
    }
    sum += __shfl_xor(sum, 16);
    sum += __shfl_xor(sum, 32);
    float inv = 1.f / sum;
    unsigned plo[14], phi[14];
    #pragma unroll
    for (int kf = 0; kf < 14; ++kf) {
      plo[kf] = (unsigned)f2bf(sc[kf][0] * inv) | ((unsigned)f2bf(sc[kf][1] * inv) << 16);
      phi[kf] = (unsigned)f2bf(sc[kf][2] * inv) | ((unsigned)f2bf(sc[kf][3] * inv) << 16);
    }
    f32x4 oacc[4] = {};
    #pragma unroll
    for (int ks = 0; ks < 7; ++ks) {
      uint2v vr[4][2];
      int sk0 = ks * 8 + cg * 2, sk1 = sk0 + 1;
      #pragma unroll
      for (int nf = 0; nf < 4; ++nf) {
        vr[nf][0] = ds_tr16(vbase + (unsigned)(((sk0 * 4 + (nf ^ (sk0 & 3))) << 7) + l15 * 8));
        vr[nf][1] = ds_tr16(vbase + (unsigned)(((sk1 * 4 + (nf ^ (sk1 & 3))) << 7) + l15 * 8));
      }
      int src0 = ((cg & 1) << 5) + l15, src1 = src0 + 16;
      int lo0 = __shfl((int)plo[2 * ks], src0),     hi0 = __shfl((int)phi[2 * ks], src0);
      int lo1 = __shfl((int)plo[2 * ks + 1], src0), hi1 = __shfl((int)phi[2 * ks + 1], src0);
      int lo0b = __shfl((int)plo[2 * ks], src1),     hi0b = __shfl((int)phi[2 * ks], src1);
      int lo1b = __shfl((int)plo[2 * ks + 1], src1), hi1b = __shfl((int)phi[2 * ks + 1], src1);
      bool hg = (cg >> 1) & 1;
      vi4 paw = { hg ? lo1 : lo0, hg ? hi1 : hi0, hg ? lo1b : lo0b, hg ? hi1b : hi0b };
      bf16x8 pa = __builtin_bit_cast(bf16x8, paw);
      asm volatile("s_waitcnt lgkmcnt(0)" ::: "memory");
      __builtin_amdgcn_sched_barrier(0);
      #pragma unroll
      for (int nf = 0; nf < 4; ++nf) {
        vi4 bw = { (int)vr[nf][0][0], (int)vr[nf][0][1], (int)vr[nf][1][0], (int)vr[nf][1][1] };
        oacc[nf] = __builtin_amdgcn_mfma_f32_16x16x32_bf16(pa, __builtin_bit_cast(bf16x8, bw), oacc[nf], 0, 0, 0);
      }
    }
    #pragma unroll
    for (int nf = 0; nf < 4; ++nf) {
      int d = h * 64 + nf * 16 + l15;
      #pragma unroll
      for (int r = 0; r < 4; ++r) {
        int qo = q0 + cg * 4 + r;
        if (qo < 223) O[(rowbase + qo) * 768 + d] = f2bf(oacc[nf][r]);
      }
    }
  }
}

// ---------------- fused residual + LayerNorm: one WAVE per row ----------------
// NADD=2: xnew = X + P0 + P1 (P1 = P0 + ps); optionally write xnew back; H = LN(xnew).
template<int NADD, bool MAP27, bool WRITEX>
__global__ __launch_bounds__(256) void ln_kernel(
    const float* __restrict__ X, const float* __restrict__ P, long ps,
    float* __restrict__ Xout, u16* __restrict__ Hb,
    const float* __restrict__ w, const float* __restrict__ bb, int nrows)
{
  int row = blockIdx.x * 4 + (threadIdx.x >> 6);
  if (row >= nrows) return;
  int xr = MAP27 ? (row / 27) * 223 + (row % 27) : row;
  int l = threadIdx.x & 63;
  const float4* xp = (const float4*)(X + (long)xr * 768);
  float4 a = xp[l], c = xp[l + 64], d = xp[l + 128];
  if (NADD == 2) {
    const float4* p0 = (const float4*)(P + (long)xr * 768);
    const float4* p1 = (const float4*)(P + ps + (long)xr * 768);
    float4 u0 = p0[l], u1 = p0[l + 64], u2 = p0[l + 128];
    float4 v0 = p1[l], v1 = p1[l + 64], v2 = p1[l + 128];
    a.x += u0.x + v0.x; a.y += u0.y + v0.y; a.z += u0.z + v0.z; a.w += u0.w + v0.w;
    c.x += u1.x + v1.x; c.y += u1.y + v1.y; c.z += u1.z + v1.z; c.w += u1.w + v1.w;
    d.x += u2.x + v2.x; d.y += u2.y + v2.y; d.z += u2.z + v2.z; d.w += u2.w + v2.w;
  }
  if (WRITEX) {
    float4* xo = (float4*)(Xout + (long)xr * 768);
    xo[l] = a; xo[l + 64] = c; xo[l + 128] = d;
  }
  float s = a.x + a.y + a.z + a.w + c.x + c.y + c.z + c.w + d.x + d.y + d.z + d.w;
  #pragma unroll
  for (int t = 1; t < 64; t <<= 1) s += __shfl_xor(s, t);
  float mean = s * (1.f / 768.f);
  a.x -= mean; a.y -= mean; a.z -= mean; a.w -= mean;
  c.x -= mean; c.y -= mean; c.z -= mean; c.w -= mean;
  d.x -= mean; d.y -= mean; d.z -= mean; d.w -= mean;
  float q = a.x*a.x + a.y*a.y + a.z*a.z + a.w*a.w
          + c.x*c.x + c.y*c.y + c.z*c.z + c.w*c.w
          + d.x*d.x + d.y*d.y + d.z*d.z + d.w*d.w;
  #pragma unroll
  for (int t = 1; t < 64; t <<= 1) q += __shfl_xor(q, t);
  float rs = rsqrtf(q * (1.f / 768.f) + 1e-5f);
  const float4* wp = (const float4*)w;
  const float4* bp = (const float4*)bb;
  u16* out = Hb + (long)row * 768;
  float4 w0 = wp[l], w1 = wp[l + 64], w2 = wp[l + 128];
  float4 b0 = bp[l], b1 = bp[l + 64], b2 = bp[l + 128];
  short4v o;
  o[0] = (short)f2bf(a.x * rs * w0.x + b0.x); o[1] = (short)f2bf(a.y * rs * w0.y + b0.y);
  o[2] = (short)f2bf(a.z * rs * w0.z + b0.z); o[3] = (short)f2bf(a.w * rs * w0.w + b0.w);
  *(short4v*)(out + l * 4) = o;
  o[0] = (short)f2bf(c.x * rs * w1.x + b1.x); o[1] = (short)f2bf(c.y * rs * w1.y + b1.y);
  o[2] = (short)f2bf(c.z * rs * w1.z + b1.z); o[3] = (short)f2bf(c.w * rs * w1.w + b1.w);
  *(short4v*)(out + 256 + l * 4) = o;
  o[0] = (short)f2bf(d.x * rs * w2.x + b2.x); o[1] = (short)f2bf(d.y * rs * w2.y + b2.y);
  o[2] = (short)f2bf(d.z * rs * w2.z + b2.z); o[3] = (short)f2bf(d.w * rs * w2.w + b2.w);
  *(short4v*)(out + 512 + l * 4) = o;
}

// ---------------- weight transpose + f32->bf16: W[K][N] -> WT[N][K], batched over z ----------------
__global__ __launch_bounds__(256) void transpose_w(
    const float* __restrict__ W, u16* __restrict__ WT, int K, int N, long sW, long sT)
{
  __shared__ float t[64][65];
  int z = blockIdx.z;
  W += (long)z * sW; WT += (long)z * sT;
  int n0 = blockIdx.x * 64, k0 = blockIdx.y * 64;
  #pragma unroll
  for (int i = 0; i < 4; ++i) {
    int flat = i * 256 + threadIdx.x;
    int r = flat >> 4, c = (flat & 15) * 4;
    float4 v = *(const float4*)(W + (long)(k0 + r) * N + n0 + c);
    t[r][c] = v.x; t[r][c + 1] = v.y; t[r][c + 2] = v.z; t[r][c + 3] = v.w;
  }
  __syncthreads();
  #pragma unroll
  for (int i = 0; i < 8; ++i) {
    int flat = i * 256 + threadIdx.x;
    int rn = flat >> 5, ck = (flat & 31) * 2;
    unsigned val = (unsigned)f2bf(t[ck][rn]) | ((unsigned)f2bf(t[ck + 1][rn]) << 16);
    *(unsigned*)(WT + (long)(n0 + rn) * K + k0 + ck) = val;
  }
}

__global__ void convert_bf16(const float* __restrict__ src, u16* __restrict__ dst, int n) {
  int i = blockIdx.x * 256 + threadIdx.x;
  if (i < n) dst[i] = f2bf(src[i]);
}

__global__ __launch_bounds__(192) void patch_extract(const float* __restrict__ img, u16* __restrict__ Xp) {
  int row = blockIdx.x;
  int t = threadIdx.x;
  int pair = t >> 2, part = t & 3;
  int cch = pair >> 4, kh = pair & 15;
  int b = row / 196, hw = row % 196, gh = hw / 14, gw = hw % 14;
  float4 v = *(const float4*)(img + ((long)(b * 3 + cch) * 224 + gh * 16 + kh) * 224 + gw * 16 + part * 4);
  short4v o;
  o[0] = (short)f2bf(v.x); o[1] = (short)f2bf(v.y); o[2] = (short)f2bf(v.z); o[3] = (short)f2bf(v.w);
  *(short4v*)(Xp + (long)row * 768 + pair * 16 + part * 4) = o;
}

__global__ void cls_pos_fill(const float* __restrict__ cls, const float* __restrict__ pos, float* __restrict__ x) {
  int i = blockIdx.x * 256 + threadIdx.x;
  if (i >= 16 * 27 * 768) return;
  int d = i % 768, t = i / 768, b = t / 27, s = t % 27;
  x[((long)b * 223 + s) * 768 + d] = cls[s * 768 + d] + pos[s * 768 + d];
}

__global__ __launch_bounds__(256) void sents_norm(const float* __restrict__ s, float* __restrict__ sn) {
  __shared__ float sb[4];
  int b = blockIdx.x, t = threadIdx.x;
  float v0 = s[b * 512 + t], v1 = s[b * 512 + t + 256];
  float q = v0 * v0 + v1 * v1;
  #pragma unroll
  for (int d = 1; d < 64; d <<= 1) q += __shfl_xor(q, d);
  if ((t & 63) == 0) sb[t >> 6] = q;
  __syncthreads();
  float inv = rsqrtf(sb[0] + sb[1] + sb[2] + sb[3]);
  sn[b * 512 + t] = v0 * inv;
  sn[b * 512 + t + 256] = v1 * inv;
}

__global__ __launch_bounds__(256) void obj_dot(const float* __restrict__ obj, const float* __restrict__ sn, float* __restrict__ pid) {
  __shared__ float sb[8];
  int r = blockIdx.x, t = threadIdx.x, b = r / 27;
  float v0 = obj[(long)r * 512 + t], v1 = obj[(long)r * 512 + t + 256];
  float w0 = sn[b * 512 + t], w1 = sn[b * 512 + t + 256];
  float q = v0 * v0 + v1 * v1;
  float dt = v0 * w0 + v1 * w1;
  #pragma unroll
  for (int d = 1; d < 64; d <<= 1) { q += __shfl_xor(q, d); dt += __shfl_xor(dt, d); }
  if ((t & 63) == 0) { sb[t >> 6] = q; sb[4 + (t >> 6)] = dt; }
  __syncthreads();
  if (t == 0) pid[r] = (sb[4] + sb[5] + sb[6] + sb[7]) * rsqrtf(sb[0] + sb[1] + sb[2] + sb[3]);
}

__global__ void gather_pred(const int* __restrict__ om, const float* __restrict__ pid, float* __restrict__ out) {
  int i = blockIdx.x * 256 + threadIdx.x;
  if (i >= 16 * 224 * 224) return;
  int b = i / (224 * 224);
  out[i] = pid[b * 27 + om[i]];
}

extern "C" void kernel_launch(void* const* d_in, const int* in_sizes, int n_in,
                              void* d_out, int out_size, void* d_ws, size_t ws_size,
                              hipStream_t stream) {
  const float* img     = (const float*)d_in[0];
  const float* sents   = (const float*)d_in[1];
  const int*   aom     = (const int*)d_in[2];
  const int*   omask   = (const int*)d_in[3];
  const float* cls     = (const float*)d_in[4];
  const float* patch_w = (const float*)d_in[5];
  const float* patch_b = (const float*)d_in[6];
  const float* pos     = (const float*)d_in[7];
  const float* ln1w    = (const float*)d_in[8];
  const float* ln1b    = (const float*)d_in[9];
  const float* qkvw    = (const float*)d_in[10];
  const float* qkvb    = (const float*)d_in[11];
  const float* outw    = (const float*)d_in[12];
  const float* outb    = (const float*)d_in[13];
  const float* ln2w    = (const float*)d_in[14];
  const float* ln2b    = (const float*)d_in[15];
  const float* m1w     = (const float*)d_in[16];
  const float* m1b     = (const float*)d_in[17];
  const float* m2w     = (const float*)d_in[18];
  const float* m2b     = (const float*)d_in[19];
  const float* lnpw    = (const float*)d_in[20];
  const float* lnpb    = (const float*)d_in[21];
  const float* projw   = (const float*)d_in[22];

  char* p = (char*)d_ws;
  auto alloc = [&](size_t bytes) { char* r = p; p += (bytes + 255) & ~(size_t)255; return r; };
  const long PS = 3584l * 768;
  float* x   = (float*)alloc(3568ul * 768 * 4);
  u16* H     = (u16*)alloc(3584ul * 768 * 2);
  u16* QKV   = (u16*)alloc(3584ul * 2304 * 2);
  u16* Obuf  = (u16*)alloc(3584ul * 768 * 2);
  u16* G     = (u16*)alloc(3584ul * 3072 * 2);
  float* Y   = (float*)alloc((size_t)PS * 2 * 4);
  float* Mp  = (float*)alloc((size_t)PS * 2 * 4);
  u16* PWc   = (u16*)alloc(768ul * 768 * 2);
  u16* PrT   = (u16*)alloc(512ul * 768 * 2);
  float* obj = (float*)alloc(432ul * 512 * 4);
  float* sn  = (float*)alloc(16ul * 512 * 4);
  float* pid = (float*)alloc(432ul * 4);

  const size_t wlayer = (2304ul * 768 + 768ul * 768 + 3072ul * 768 + 768ul * 3072) * 2;
  size_t used = (size_t)(p - (char*)d_ws);
  int nw = (ws_size >= used + 12 * wlayer + 65536) ? 12 : 1;
  const long sQ = 2304l * 768, sO = 768l * 768, s1 = 768l * 3072, s2 = 3072l * 768;
  u16* WqT = (u16*)alloc((size_t)sQ * 2 * nw);
  u16* WoT = (u16*)alloc((size_t)sO * 2 * nw);
  u16* W1T = (u16*)alloc((size_t)s1 * 2 * nw);
  u16* W2T = (u16*)alloc((size_t)s2 * 2 * nw);

  convert_bf16<<<2304, 256, 0, stream>>>(patch_w, PWc, 768 * 768);
  transpose_w<<<dim3(8, 12, 1), 256, 0, stream>>>(projw, PrT, 768, 512, 0, 0);
  if (nw == 12) {
    transpose_w<<<dim3(36, 12, 12), 256, 0, stream>>>(qkvw, WqT, 768, 2304, sQ, sQ);
    transpose_w<<<dim3(12, 12, 12), 256, 0, stream>>>(outw, WoT, 768, 768, sO, sO);
    transpose_w<<<dim3(48, 12, 12), 256, 0, stream>>>(m1w, W1T, 768, 3072, s1, s1);
    transpose_w<<<dim3(12, 48, 12), 256, 0, stream>>>(m2w, W2T, 3072, 768, s2, s2);
  }
  patch_extract<<<3136, 192, 0, stream>>>(img, H);
  cls_pos_fill<<<1296, 256, 0, stream>>>(cls, pos, x);
  gemm_bt<64, 3, false, 1><<<dim3(12, 25), 256, 0, stream>>>(H, PWc, patch_b, x, nullptr, 3136, 768, 768, pos, 0);

  for (int l = 0; l < 12; ++l) {
    u16 *wq, *wo, *w1, *w2;
    if (nw == 12) { wq = WqT + (long)l * sQ; wo = WoT + (long)l * sO; w1 = W1T + (long)l * s1; w2 = W2T + (long)l * s2; }
    else {
      wq = WqT; wo = WoT; w1 = W1T; w2 = W2T;
      transpose_w<<<dim3(36, 12, 1), 256, 0, stream>>>(qkvw + (long)l * sQ, wq, 768, 2304, 0, 0);
      transpose_w<<<dim3(12, 12, 1), 256, 0, stream>>>(outw + (long)l * sO, wo, 768, 768, 0, 0);
      transpose_w<<<dim3(48, 12, 1), 256, 0, stream>>>(m1w + (long)l * s1, w1, 768, 3072, 0, 0);
      transpose_w<<<dim3(12, 48, 1), 256, 0, stream>>>(m2w + (long)l * s2, w2, 3072, 768, 0, 0);
    }
    if (l == 0)
      ln_kernel<0, false, false><<<892, 256, 0, stream>>>(x, nullptr, 0, nullptr, H, ln1w, ln1b, 3568);
    else
      ln_kernel<2, false, true><<<892, 256, 0, stream>>>(x, Mp, PS, x, H, ln1w + l * 768, ln1b + l * 768, 3568);
    gemm_bt<128, 0, false, 1><<<dim3(18, 28), 256, 0, stream>>>(H, wq, qkvb + l * 2304, nullptr, QKV, 3568, 2304, 768, nullptr, 0);
    attn_kernel<<<dim3(2, 12, 16), 256, 0, stream>>>(QKV, aom, Obuf);
    gemm_bt<64, 2, false, 2><<<dim3(12, 28, 2), 256, 0, stream>>>(Obuf, wo, outb + l * 768, Y, nullptr, 3568, 768, 768, nullptr, PS);
    ln_kernel<2, false, true><<<892, 256, 0, stream>>>(x, Y, PS, x, H, ln2w + l * 768, ln2b + l * 768, 3568);
    gemm_bt<128, 0, true, 1><<<dim3(24, 28), 256, 0, stream>>>(H, w1, m1b + l * 3072, nullptr, G, 3568, 3072, 768, nullptr, 0);
    gemm_bt<64, 2, false, 2><<<dim3(12, 28, 2), 256, 0, stream>>>(G, w2, m2b + l * 768, Mp, nullptr, 3568, 768, 3072, nullptr, PS);
  }

  ln_kernel<2, true, false><<<108, 256, 0, stream>>>(x, Mp, PS, nullptr, H, lnpw, lnpb, 432);
  gemm_bt<64, 2, false, 1><<<dim3(8, 4), 256, 0, stream>>>(H, PrT, nullptr, obj, nullptr, 432, 512, 768, nullptr, 0);
  sents_norm<<<16, 256, 0, stream>>>(sents, sn);
  obj_dot<<<432, 256, 0, stream>>>(obj, sn, pid);
  gather_pred<<<3136, 256, 0, stream>>>(omask, pid, (float*)d_out);
}

// Round 11
// 2138.121 us; speedup vs baseline: 1.1045x; 1.0004x over previous
//
#include <hip/hip_runtime.h>

#define DEV __device__ __forceinline__

typedef short bf16x8 __attribute__((ext_vector_type(8)));
typedef float f32x4 __attribute__((ext_vector_type(4)));
typedef int vi4 __attribute__((ext_vector_type(4)));
typedef unsigned uint2v __attribute__((ext_vector_type(2)));
typedef unsigned short u16;
typedef short short4v __attribute__((ext_vector_type(4)));

#define NEGV -1000000000.0f

DEV u16 f2bf(float f) {
  union { float f; unsigned u; } v; v.f = f;
  unsigned r = v.u + 0x7FFFu + ((v.u >> 16) & 1u);
  return (u16)(r >> 16);
}

DEV bf16x8 ld_bf8(const u16* p) {
  vi4 v = *(const vi4*)p;
  return __builtin_bit_cast(bf16x8, v);
}

DEV void gload_lds16(const u16* g, vi4* l) {
  __builtin_amdgcn_global_load_lds((const __attribute__((address_space(1))) void*)g,
                                   (__attribute__((address_space(3))) void*)l, 16, 0, 0);
}

DEV unsigned lds_off(const void* p) {
  return (unsigned)(unsigned long long)(const __attribute__((address_space(3))) void*)p;
}

DEV uint2v ds_tr16(unsigned byteaddr) {
  uint2v r;
  asm volatile("ds_read_b64_tr_b16 %0, %1" : "=v"(r) : "v"(byteaddr));
  return r;
}

// ---------------- generic GEMM: C[M,N] = A[Mpad,K](bf16) @ Bt[N,K](bf16)^T ----------------
// BK=64, 2-buffer pipeline, counted vmcnt. A rows PADDED to mult of 128.
// MODE 0: Cb = bf16(acc+bias); MODE 2: Cf[+bz*pstride] = acc (+bias@z0) — split-K partials,
// no atomics (summed by following fused-LN / norm_dot kernel); MODE 3: patch-embed scatter.
template<int BN, int MODE, bool GELU, int KS>
__global__ __launch_bounds__(256) void gemm_bt(
    const u16* __restrict__ A, const u16* __restrict__ Bt,
    const float* __restrict__ bias,
    float* __restrict__ Cf, u16* __restrict__ Cb,
    int M, int N, int K, const float* __restrict__ pos, long pstride)
{
  constexpr int FJ = BN / 32;
  constexpr int LTOT = 4 + FJ;
  __shared__ vi4 As[2][1024];
  __shared__ vi4 Bs[2][BN * 8];

  // bijective XCD-aware swizzle (m204)
  int gx = gridDim.x, gy = gridDim.y;
  int nwg = gx * gy * (int)gridDim.z;
  int orig = blockIdx.x + gx * (blockIdx.y + gy * blockIdx.z);
  int qq = nwg >> 3, rr = nwg & 7;
  int xcd = orig & 7, off = orig >> 3;
  int id = (xcd < rr) ? xcd * (qq + 1) + off : rr * (qq + 1) + (xcd - rr) * qq + off;
  int bx = id % gx, rest = id / gx, by = rest % gy, bz = rest / gy;

  int tid = threadIdx.x, lane = tid & 63, wid = tid >> 6;
  int wm = wid >> 1, wn = wid & 1;
  int m0 = by * 128, n0 = bx * BN;
  int kBeg = (K / KS) * bz;
  int nT = (K / KS) >> 6;
  f32x4 acc[4][FJ] = {};

  auto STAGE = [&](int buf, int kk) {
    #pragma unroll
    for (int r = 0; r < 4; ++r) {
      int flat = r * 256 + tid;
      int row = flat >> 3, c = flat & 7;
      int cs = c ^ (row & 7);
      gload_lds16(A + (long)(m0 + row) * K + kk + cs * 8, &As[buf][r * 256 + wid * 64]);
    }
    #pragma unroll
    for (int r = 0; r < FJ; ++r) {
      int flat = r * 256 + tid;
      int row = flat >> 3, c = flat & 7;
      int cs = c ^ (row & 7);
      gload_lds16(Bt + (long)(n0 + row) * K + kk + cs * 8, &Bs[buf][r * 256 + wid * 64]);
    }
  };

  STAGE(0, kBeg);
  int cur = 0;
  for (int t = 0; t < nT; ++t) {
    if (t + 1 < nT) {
      STAGE(cur ^ 1, kBeg + (t + 1) * 64);
      asm volatile("s_waitcnt vmcnt(%0)" :: "i"(LTOT) : "memory");
    } else {
      asm volatile("s_waitcnt vmcnt(0)" ::: "memory");
    }
    __builtin_amdgcn_s_barrier();
    int cg = lane >> 4, l15 = lane & 15;
    #pragma unroll
    for (int ks = 0; ks < 2; ++ks) {
      bf16x8 af[4], bfr[FJ];
      #pragma unroll
      for (int i = 0; i < 4; ++i) {
        int ra = wm * 64 + i * 16 + l15;
        af[i] = __builtin_bit_cast(bf16x8, As[cur][ra * 8 + ((ks * 4 + cg) ^ (ra & 7))]);
      }
      #pragma unroll
      for (int j = 0; j < FJ; ++j) {
        int rb = wn * (BN / 2) + j * 16 + l15;
        bfr[j] = __builtin_bit_cast(bf16x8, Bs[cur][rb * 8 + ((ks * 4 + cg) ^ (rb & 7))]);
      }
      #pragma unroll
      for (int i = 0; i < 4; ++i)
        #pragma unroll
        for (int j = 0; j < FJ; ++j)
          acc[i][j] = __builtin_amdgcn_mfma_f32_16x16x32_bf16(af[i], bfr[j], acc[i][j], 0, 0, 0);
    }
    __builtin_amdgcn_s_barrier();
    cur ^= 1;
  }

  int cg = lane >> 4, l15 = lane & 15;
  float* Cfz = (MODE == 2 && KS > 1) ? Cf + (long)bz * pstride : Cf;
  #pragma unroll
  for (int i = 0; i < 4; ++i) {
    #pragma unroll
    for (int j = 0; j < FJ; ++j) {
      int col = n0 + wn * (BN / 2) + j * 16 + l15;
      float bv = bias ? bias[col] : 0.f;
      #pragma unroll
      for (int r = 0; r < 4; ++r) {
        int row = m0 + wm * 64 + i * 16 + cg * 4 + r;
        if (row < M) {
          float v = acc[i][j][r];
          if (KS == 1 || bz == 0) v += bv;
          if (GELU) v = v / (1.f + __expf(-1.702f * v));
          if (MODE == 0) Cb[(long)row * N + col] = f2bf(v);
          else if (MODE == 2) Cfz[(long)row * N + col] = v;
          else {
            int hw = row % 196;
            int xr = (row / 196) * 223 + 27 + hw;
            Cf[(long)xr * 768 + col] = v + pos[(27 + hw) * 768 + col];
          }
        }
      }
    }
  }
}

// ---------------- attention (swapped QK^T, in-register P, tr_b16 V reads) ----------------
// grid (2 qhalves, 12 heads, 16 batch); block 256. XCD-pair swizzle keeps both qg of one
// (h,b) on one XCD. Q loads hoisted before the staging barrier (latency hidden).
__global__ __launch_bounds__(256) void attn_kernel(
    const u16* __restrict__ QKV, const int* __restrict__ aom, u16* __restrict__ O)
{
  __shared__ vi4 Kl[224 * 8];   // K row-major [key][8 chunks], chunk XOR (key&7)
  __shared__ vi4 Vl[224 * 8];   // V subtiled [sk][sd^(sk&3)][4 keys][16 d] (128B subtiles)
  __shared__ int ml[196];
  int tid = threadIdx.x, lane = tid & 63, wid = tid >> 6;
  // m204 swizzle, nwg = 384 (384 % 8 == 0): id = (orig&7)*48 + orig>>3
  int orig = blockIdx.x + 2 * (blockIdx.y + 12 * blockIdx.z);
  int id = (orig & 7) * 48 + (orig >> 3);
  int qg = id & 1, h = (id >> 1) % 12, b = id / 24;
  long rowbase = (long)b * 223;
  #pragma unroll
  for (int it = 0; it < 7; ++it) {
    int flat = it * 256 + tid;
    int s = flat >> 3, c = flat & 7;
    int cs = c ^ (s & 7);
    gload_lds16(QKV + (rowbase + s) * 2304 + 768 + h * 64 + cs * 8, &Kl[it * 256 + wid * 64]);
  }
  #pragma unroll
  for (int it = 0; it < 7; ++it) {
    int u = it * 256 + tid;
    int slin = u >> 3, inner = u & 7;
    int sk = slin >> 2, sdp = slin & 3;
    int s = sk * 4 + (inner >> 1);
    int c = ((sdp ^ (sk & 3)) << 1) | (inner & 1);
    gload_lds16(QKV + (rowbase + s) * 2304 + 1536 + h * 64 + c * 8, &Vl[it * 256 + wid * 64]);
  }
  for (int i = tid; i < 196; i += 256) ml[i] = aom[b * 196 + i];

  // Q loads hoisted: issued before the staging drain, latency overlapped
  int l15 = lane & 15, cg = lane >> 4;
  bf16x8 aq[2][2];
  #pragma unroll
  for (int rep = 0; rep < 2; ++rep) {
    int fo = wid * 2 + rep;
    int qf = qg * 7 + (fo < 7 ? fo : 6);
    int arow = qf * 16 + l15; if (arow > 222) arow = 222;
    const u16* qb = QKV + (rowbase + arow) * 2304 + h * 64;
    aq[rep][0] = ld_bf8(qb + cg * 8);
    aq[rep][1] = ld_bf8(qb + 32 + cg * 8);
  }
  __syncthreads();

  unsigned vbase = lds_off(Vl);
  #pragma unroll
  for (int rep = 0; rep < 2; ++rep) {
    int fo = wid * 2 + rep;
    if (fo >= 7) break;
    int qf = qg * 7 + fo;
    int q0 = qf * 16;

    f32x4 sc[14];
    #pragma unroll
    for (int kf = 0; kf < 14; ++kf) {
      int key = kf * 16 + l15;
      f32x4 a = {0.f, 0.f, 0.f, 0.f};
      bf16x8 bk0 = __builtin_bit_cast(bf16x8, Kl[key * 8 + (cg ^ (key & 7))]);
      bf16x8 bk1 = __builtin_bit_cast(bf16x8, Kl[key * 8 + ((4 + cg) ^ (key & 7))]);
      a = __builtin_amdgcn_mfma_f32_16x16x32_bf16(bk0, aq[rep][0], a, 0, 0, 0);
      a = __builtin_amdgcn_mfma_f32_16x16x32_bf16(bk1, aq[rep][1], a, 0, 0, 0);
      sc[kf] = a;
    }
    int q = q0 + l15;
    float mx = -3.4e38f;
    #pragma unroll
    for (int kf = 0; kf < 14; ++kf) {
      #pragma unroll
      for (int r = 0; r < 4; ++r) {
        int key = kf * 16 + cg * 4 + r;
        float mval;
        if (key >= 223) mval = NEGV;
        else if (q >= 27) mval = (key < 27) ? NEGV : 0.f;
        else if (key < 27) mval = (key == q) ? 0.f : NEGV;
        else mval = (ml[key - 27] == q) ? 0.f : NEGV;
        float sv = sc[kf][r] * 0.125f + mval;
        sc[kf][r] = sv;
        mx = fmaxf(mx, sv);
      }
    }
    mx = fmaxf(mx, __shfl_xor(mx, 16));
    mx = fmaxf(mx, __shfl_xor(mx, 32));
    float sum = 0.f;
    #pragma unroll
    for (int kf = 0; kf < 14; ++kf) {
      #pragma unroll
      for (int r = 0; r < 4; ++r) {
        float e = __expf(sc[kf][r] - mx);
        sc[kf][r] = e; sum += e;
      }
    }
    sum += __shfl_xor(sum, 16);
    sum += __shfl_xor(sum, 32);
    float inv = 1.f / sum;
    unsigned plo[14], phi[14];
    #pragma unroll
    for (int kf = 0; kf < 14; ++kf) {
      plo[kf] = (unsigned)f2bf(sc[kf][0] * inv) | ((unsigned)f2bf(sc[kf][1] * inv) << 16);
      phi[kf] = (unsigned)f2bf(sc[kf][2] * inv) | ((unsigned)f2bf(sc[kf][3] * inv) << 16);
    }
    f32x4 oacc[4] = {};
    #pragma unroll
    for (int ks = 0; ks < 7; ++ks) {
      uint2v vr[4][2];
      int sk0 = ks * 8 + cg * 2, sk1 = sk0 + 1;
      #pragma unroll
      for (int nf = 0; nf < 4; ++nf) {
        vr[nf][0] = ds_tr16(vbase + (unsigned)(((sk0 * 4 + (nf ^ (sk0 & 3))) << 7) + l15 * 8));
        vr[nf][1] = ds_tr16(vbase + (unsigned)(((sk1 * 4 + (nf ^ (sk1 & 3))) << 7) + l15 * 8));
      }
      int src0 = ((cg & 1) << 5) + l15, src1 = src0 + 16;
      int lo0 = __shfl((int)plo[2 * ks], src0),     hi0 = __shfl((int)phi[2 * ks], src0);
      int lo1 = __shfl((int)plo[2 * ks + 1], src0), hi1 = __shfl((int)phi[2 * ks + 1], src0);
      int lo0b = __shfl((int)plo[2 * ks], src1),     hi0b = __shfl((int)phi[2 * ks], src1);
      int lo1b = __shfl((int)plo[2 * ks + 1], src1), hi1b = __shfl((int)phi[2 * ks + 1], src1);
      bool hg = (cg >> 1) & 1;
      vi4 paw = { hg ? lo1 : lo0, hg ? hi1 : hi0, hg ? lo1b : lo0b, hg ? hi1b : hi0b };
      bf16x8 pa = __builtin_bit_cast(bf16x8, paw);
      asm volatile("s_waitcnt lgkmcnt(0)" ::: "memory");
      __builtin_amdgcn_sched_barrier(0);
      #pragma unroll
      for (int nf = 0; nf < 4; ++nf) {
        vi4 bw = { (int)vr[nf][0][0], (int)vr[nf][0][1], (int)vr[nf][1][0], (int)vr[nf][1][1] };
        oacc[nf] = __builtin_amdgcn_mfma_f32_16x16x32_bf16(pa, __builtin_bit_cast(bf16x8, bw), oacc[nf], 0, 0, 0);
      }
    }
    #pragma unroll
    for (int nf = 0; nf < 4; ++nf) {
      int d = h * 64 + nf * 16 + l15;
      #pragma unroll
      for (int r = 0; r < 4; ++r) {
        int qo = q0 + cg * 4 + r;
        if (qo < 223) O[(rowbase + qo) * 768 + d] = f2bf(oacc[nf][r]);
      }
    }
  }
}

// ---------------- fused residual + LayerNorm: one WAVE per row ----------------
template<int NADD, bool MAP27, bool WRITEX>
__global__ __launch_bounds__(256) void ln_kernel(
    const float* __restrict__ X, const float* __restrict__ P, long ps,
    float* __restrict__ Xout, u16* __restrict__ Hb,
    const float* __restrict__ w, const float* __restrict__ bb, int nrows)
{
  int row = blockIdx.x * 4 + (threadIdx.x >> 6);
  if (row >= nrows) return;
  int xr = MAP27 ? (row / 27) * 223 + (row % 27) : row;
  int l = threadIdx.x & 63;
  const float4* xp = (const float4*)(X + (long)xr * 768);
  float4 a = xp[l], c = xp[l + 64], d = xp[l + 128];
  if (NADD == 2) {
    const float4* p0 = (const float4*)(P + (long)xr * 768);
    const float4* p1 = (const float4*)(P + ps + (long)xr * 768);
    float4 u0 = p0[l], u1 = p0[l + 64], u2 = p0[l + 128];
    float4 v0 = p1[l], v1 = p1[l + 64], v2 = p1[l + 128];
    a.x += u0.x + v0.x; a.y += u0.y + v0.y; a.z += u0.z + v0.z; a.w += u0.w + v0.w;
    c.x += u1.x + v1.x; c.y += u1.y + v1.y; c.z += u1.z + v1.z; c.w += u1.w + v1.w;
    d.x += u2.x + v2.x; d.y += u2.y + v2.y; d.z += u2.z + v2.z; d.w += u2.w + v2.w;
  }
  if (WRITEX) {
    float4* xo = (float4*)(Xout + (long)xr * 768);
    xo[l] = a; xo[l + 64] = c; xo[l + 128] = d;
  }
  float s = a.x + a.y + a.z + a.w + c.x + c.y + c.z + c.w + d.x + d.y + d.z + d.w;
  #pragma unroll
  for (int t = 1; t < 64; t <<= 1) s += __shfl_xor(s, t);
  float mean = s * (1.f / 768.f);
  a.x -= mean; a.y -= mean; a.z -= mean; a.w -= mean;
  c.x -= mean; c.y -= mean; c.z -= mean; c.w -= mean;
  d.x -= mean; d.y -= mean; d.z -= mean; d.w -= mean;
  float q = a.x*a.x + a.y*a.y + a.z*a.z + a.w*a.w
          + c.x*c.x + c.y*c.y + c.z*c.z + c.w*c.w
          + d.x*d.x + d.y*d.y + d.z*d.z + d.w*d.w;
  #pragma unroll
  for (int t = 1; t < 64; t <<= 1) q += __shfl_xor(q, t);
  float rs = rsqrtf(q * (1.f / 768.f) + 1e-5f);
  const float4* wp = (const float4*)w;
  const float4* bp = (const float4*)bb;
  u16* out = Hb + (long)row * 768;
  float4 w0 = wp[l], w1 = wp[l + 64], w2 = wp[l + 128];
  float4 b0 = bp[l], b1 = bp[l + 64], b2 = bp[l + 128];
  short4v o;
  o[0] = (short)f2bf(a.x * rs * w0.x + b0.x); o[1] = (short)f2bf(a.y * rs * w0.y + b0.y);
  o[2] = (short)f2bf(a.z * rs * w0.z + b0.z); o[3] = (short)f2bf(a.w * rs * w0.w + b0.w);
  *(short4v*)(out + l * 4) = o;
  o[0] = (short)f2bf(c.x * rs * w1.x + b1.x); o[1] = (short)f2bf(c.y * rs * w1.y + b1.y);
  o[2] = (short)f2bf(c.z * rs * w1.z + b1.z); o[3] = (short)f2bf(c.w * rs * w1.w + b1.w);
  *(short4v*)(out + 256 + l * 4) = o;
  o[0] = (short)f2bf(d.x * rs * w2.x + b2.x); o[1] = (short)f2bf(d.y * rs * w2.y + b2.y);
  o[2] = (short)f2bf(d.z * rs * w2.z + b2.z); o[3] = (short)f2bf(d.w * rs * w2.w + b2.w);
  *(short4v*)(out + 512 + l * 4) = o;
}

// ---------------- weight transpose + f32->bf16: W[K][N] -> WT[N][K], batched over z ----------------
__global__ __launch_bounds__(256) void transpose_w(
    const float* __restrict__ W, u16* __restrict__ WT, int K, int N, long sW, long sT)
{
  __shared__ float t[64][65];
  int z = blockIdx.z;
  W += (long)z * sW; WT += (long)z * sT;
  int n0 = blockIdx.x * 64, k0 = blockIdx.y * 64;
  #pragma unroll
  for (int i = 0; i < 4; ++i) {
    int flat = i * 256 + threadIdx.x;
    int r = flat >> 4, c = (flat & 15) * 4;
    float4 v = *(const float4*)(W + (long)(k0 + r) * N + n0 + c);
    t[r][c] = v.x; t[r][c + 1] = v.y; t[r][c + 2] = v.z; t[r][c + 3] = v.w;
  }
  __syncthreads();
  #pragma unroll
  for (int i = 0; i < 8; ++i) {
    int flat = i * 256 + threadIdx.x;
    int rn = flat >> 5, ck = (flat & 31) * 2;
    unsigned val = (unsigned)f2bf(t[ck][rn]) | ((unsigned)f2bf(t[ck + 1][rn]) << 16);
    *(unsigned*)(WT + (long)(n0 + rn) * K + k0 + ck) = val;
  }
}

__global__ void convert_bf16(const float* __restrict__ src, u16* __restrict__ dst, int n4) {
  int i = blockIdx.x * 256 + threadIdx.x;
  if (i < n4) {
    float4 v = ((const float4*)src)[i];
    short4v o;
    o[0] = (short)f2bf(v.x); o[1] = (short)f2bf(v.y); o[2] = (short)f2bf(v.z); o[3] = (short)f2bf(v.w);
    *(short4v*)(dst + i * 4) = o;
  }
}

__global__ __launch_bounds__(192) void patch_extract(const float* __restrict__ img, u16* __restrict__ Xp) {
  int row = blockIdx.x;
  int t = threadIdx.x;
  int pair = t >> 2, part = t & 3;
  int cch = pair >> 4, kh = pair & 15;
  int b = row / 196, hw = row % 196, gh = hw / 14, gw = hw % 14;
  float4 v = *(const float4*)(img + ((long)(b * 3 + cch) * 224 + gh * 16 + kh) * 224 + gw * 16 + part * 4);
  short4v o;
  o[0] = (short)f2bf(v.x); o[1] = (short)f2bf(v.y); o[2] = (short)f2bf(v.z); o[3] = (short)f2bf(v.w);
  *(short4v*)(Xp + (long)row * 768 + pair * 16 + part * 4) = o;
}

__global__ void cls_pos_fill(const float* __restrict__ cls, const float* __restrict__ pos, float* __restrict__ x) {
  int i = blockIdx.x * 256 + threadIdx.x;
  if (i >= 16 * 27 * 768) return;
  int d = i % 768, t = i / 768, b = t / 27, s = t % 27;
  x[((long)b * 223 + s) * 768 + d] = cls[s * 768 + d] + pos[s * 768 + d];
}

// fused: obj = P0+P1 (head split-K partials); pid = (obj/|obj|)·(sents/|sents|)
__global__ __launch_bounds__(256) void norm_dot(
    const float* __restrict__ objp, long ps, const float* __restrict__ sents,
    float* __restrict__ pid)
{
  __shared__ float sb[12];
  int r = blockIdx.x, t = threadIdx.x, b = r / 27;
  long base = (long)r * 512;
  float v0 = objp[base + t] + objp[ps + base + t];
  float v1 = objp[base + t + 256] + objp[ps + base + t + 256];
  float w0 = sents[b * 512 + t], w1 = sents[b * 512 + t + 256];
  float q = v0 * v0 + v1 * v1;
  float dt = v0 * w0 + v1 * w1;
  float sw = w0 * w0 + w1 * w1;
  #pragma unroll
  for (int d = 1; d < 64; d <<= 1) {
    q += __shfl_xor(q, d); dt += __shfl_xor(dt, d); sw += __shfl_xor(sw, d);
  }
  if ((t & 63) == 0) { sb[t >> 6] = q; sb[4 + (t >> 6)] = dt; sb[8 + (t >> 6)] = sw; }
  __syncthreads();
  if (t == 0)
    pid[r] = (sb[4] + sb[5] + sb[6] + sb[7])
           * rsqrtf(sb[0] + sb[1] + sb[2] + sb[3])
           * rsqrtf(sb[8] + sb[9] + sb[10] + sb[11]);
}

__global__ void gather_pred(const int* __restrict__ om, const float* __restrict__ pid, float* __restrict__ out) {
  int i = blockIdx.x * 256 + threadIdx.x;
  if (i >= 16 * 224 * 224) return;
  int b = i / (224 * 224);
  out[i] = pid[b * 27 + om[i]];
}

extern "C" void kernel_launch(void* const* d_in, const int* in_sizes, int n_in,
                              void* d_out, int out_size, void* d_ws, size_t ws_size,
                              hipStream_t stream) {
  const float* img     = (const float*)d_in[0];
  const float* sents   = (const float*)d_in[1];
  const int*   aom     = (const int*)d_in[2];
  const int*   omask   = (const int*)d_in[3];
  const float* cls     = (const float*)d_in[4];
  const float* patch_w = (const float*)d_in[5];
  const float* patch_b = (const float*)d_in[6];
  const float* pos     = (const float*)d_in[7];
  const float* ln1w    = (const float*)d_in[8];
  const float* ln1b    = (const float*)d_in[9];
  const float* qkvw    = (const float*)d_in[10];
  const float* qkvb    = (const float*)d_in[11];
  const float* outw    = (const float*)d_in[12];
  const float* outb    = (const float*)d_in[13];
  const float* ln2w    = (const float*)d_in[14];
  const float* ln2b    = (const float*)d_in[15];
  const float* m1w     = (const float*)d_in[16];
  const float* m1b     = (const float*)d_in[17];
  const float* m2w     = (const float*)d_in[18];
  const float* m2b     = (const float*)d_in[19];
  const float* lnpw    = (const float*)d_in[20];
  const float* lnpb    = (const float*)d_in[21];
  const float* projw   = (const float*)d_in[22];

  char* p = (char*)d_ws;
  auto alloc = [&](size_t bytes) { char* r = p; p += (bytes + 255) & ~(size_t)255; return r; };
  const long PS = 3584l * 768;
  const long OPS = 432l * 512;
  float* x   = (float*)alloc(3568ul * 768 * 4);
  u16* H     = (u16*)alloc(3584ul * 768 * 2);
  u16* QKV   = (u16*)alloc(3584ul * 2304 * 2);
  u16* Obuf  = (u16*)alloc(3584ul * 768 * 2);
  u16* G     = (u16*)alloc(3584ul * 3072 * 2);
  float* Y   = (float*)alloc((size_t)PS * 2 * 4);
  float* Mp  = (float*)alloc((size_t)PS * 2 * 4);
  u16* PWc   = (u16*)alloc(768ul * 768 * 2);
  u16* PrT   = (u16*)alloc(512ul * 768 * 2);
  float* obj = (float*)alloc((size_t)OPS * 2 * 4);
  float* pid = (float*)alloc(432ul * 4);

  const size_t wlayer = (2304ul * 768 + 768ul * 768 + 3072ul * 768 + 768ul * 3072) * 2;
  size_t used = (size_t)(p - (char*)d_ws);
  int nw = (ws_size >= used + 12 * wlayer + 65536) ? 12 : 1;
  const long sQ = 2304l * 768, sO = 768l * 768, s1 = 768l * 3072, s2 = 3072l * 768;
  u16* WqT = (u16*)alloc((size_t)sQ * 2 * nw);
  u16* WoT = (u16*)alloc((size_t)sO * 2 * nw);
  u16* W1T = (u16*)alloc((size_t)s1 * 2 * nw);
  u16* W2T = (u16*)alloc((size_t)s2 * 2 * nw);

  convert_bf16<<<576, 256, 0, stream>>>(patch_w, PWc, 147456);
  transpose_w<<<dim3(8, 12, 1), 256, 0, stream>>>(projw, PrT, 768, 512, 0, 0);
  if (nw == 12) {
    transpose_w<<<dim3(36, 12, 12), 256, 0, stream>>>(qkvw, WqT, 768, 2304, sQ, sQ);
    transpose_w<<<dim3(12, 12, 12), 256, 0, stream>>>(outw, WoT, 768, 768, sO, sO);
    transpose_w<<<dim3(48, 12, 12), 256, 0, stream>>>(m1w, W1T, 768, 3072, s1, s1);
    transpose_w<<<dim3(12, 48, 12), 256, 0, stream>>>(m2w, W2T, 3072, 768, s2, s2);
  }
  patch_extract<<<3136, 192, 0, stream>>>(img, H);
  cls_pos_fill<<<1296, 256, 0, stream>>>(cls, pos, x);
  gemm_bt<64, 3, false, 1><<<dim3(12, 25), 256, 0, stream>>>(H, PWc, patch_b, x, nullptr, 3136, 768, 768, pos, 0);

  for (int l = 0; l < 12; ++l) {
    u16 *wq, *wo, *w1, *w2;
    if (nw == 12) { wq = WqT + (long)l * sQ; wo = WoT + (long)l * sO; w1 = W1T + (long)l * s1; w2 = W2T + (long)l * s2; }
    else {
      wq = WqT; wo = WoT; w1 = W1T; w2 = W2T;
      transpose_w<<<dim3(36, 12, 1), 256, 0, stream>>>(qkvw + (long)l * sQ, wq, 768, 2304, 0, 0);
      transpose_w<<<dim3(12, 12, 1), 256, 0, stream>>>(outw + (long)l * sO, wo, 768, 768, 0, 0);
      transpose_w<<<dim3(48, 12, 1), 256, 0, stream>>>(m1w + (long)l * s1, w1, 768, 3072, 0, 0);
      transpose_w<<<dim3(12, 48, 1), 256, 0, stream>>>(m2w + (long)l * s2, w2, 3072, 768, 0, 0);
    }
    if (l == 0)
      ln_kernel<0, false, false><<<892, 256, 0, stream>>>(x, nullptr, 0, nullptr, H, ln1w, ln1b, 3568);
    else
      ln_kernel<2, false, true><<<892, 256, 0, stream>>>(x, Mp, PS, x, H, ln1w + l * 768, ln1b + l * 768, 3568);
    gemm_bt<128, 0, false, 1><<<dim3(18, 28), 256, 0, stream>>>(H, wq, qkvb + l * 2304, nullptr, QKV, 3568, 2304, 768, nullptr, 0);
    attn_kernel<<<dim3(2, 12, 16), 256, 0, stream>>>(QKV, aom, Obuf);
    gemm_bt<64, 2, false, 2><<<dim3(12, 28, 2), 256, 0, stream>>>(Obuf, wo, outb + l * 768, Y, nullptr, 3568, 768, 768, nullptr, PS);
    ln_kernel<2, false, true><<<892, 256, 0, stream>>>(x, Y, PS, x, H, ln2w + l * 768, ln2b + l * 768, 3568);
    gemm_bt<128, 0, true, 1><<<dim3(24, 28), 256, 0, stream>>>(H, w1, m1b + l * 3072, nullptr, G, 3568, 3072, 768, nullptr, 0);
    gemm_bt<64, 2, false, 2><<<dim3(12, 28, 2), 256, 0, stream>>>(G, w2, m2b + l * 768, Mp, nullptr, 3568, 768, 3072, nullptr, PS);
  }

  ln_kernel<2, true, false><<<108, 256, 0, stream>>>(x, Mp, PS, nullptr, H, lnpw, lnpb, 432);
  gemm_bt<64, 2, false, 2><<<dim3(8, 4, 2), 256, 0, stream>>>(H, PrT, nullptr, obj, nullptr, 432, 512, 768, nullptr, OPS);
  norm_dot<<<432, 256, 0, stream>>>(obj, OPS, sents, pid);
  gather_pred<<<3136, 256, 0, stream>>>(omask, pid, (float*)d_out);
}

// Round 12
// 2067.986 us; speedup vs baseline: 1.1419x; 1.0339x over previous
//
#include <hip/hip_runtime.h>

#define DEV __device__ __forceinline__

typedef short bf16x8 __attribute__((ext_vector_type(8)));
typedef float f32x4 __attribute__((ext_vector_type(4)));
typedef int vi4 __attribute__((ext_vector_type(4)));
typedef unsigned uint2v __attribute__((ext_vector_type(2)));
typedef unsigned short u16;
typedef short short4v __attribute__((ext_vector_type(4)));

#define NEGV -1000000000.0f

DEV u16 f2bf(float f) {
  union { float f; unsigned u; } v; v.f = f;
  unsigned r = v.u + 0x7FFFu + ((v.u >> 16) & 1u);
  return (u16)(r >> 16);
}

DEV float b2f(u16 s) {
  union { unsigned u; float f; } v; v.u = ((unsigned)s) << 16;
  return v.f;
}

DEV bf16x8 ld_bf8(const u16* p) {
  vi4 v = *(const vi4*)p;
  return __builtin_bit_cast(bf16x8, v);
}

DEV void gload_lds16(const u16* g, vi4* l) {
  __builtin_amdgcn_global_load_lds((const __attribute__((address_space(1))) void*)g,
                                   (__attribute__((address_space(3))) void*)l, 16, 0, 0);
}

DEV unsigned lds_off(const void* p) {
  return (unsigned)(unsigned long long)(const __attribute__((address_space(3))) void*)p;
}

DEV uint2v ds_tr16(unsigned byteaddr) {
  uint2v r;
  asm volatile("ds_read_b64_tr_b16 %0, %1" : "=v"(r) : "v"(byteaddr));
  return r;
}

// ---------------- generic GEMM: C[M,N] = A[Mpad,K](bf16) @ Bt[N,K](bf16)^T ----------------
// BK=64, 2-buffer pipeline, counted vmcnt. A rows PADDED to mult of 128.
// MODE 0: Cb = bf16(acc+bias); MODE 2: Cf[+bz*pstride] = acc (+bias@z0) f32 split-K partials;
// MODE 4: Cb[+bz*pstride] = bf16(acc (+bias@z0)) bf16 split-K partials (summed by fused LN);
// MODE 3: patch-embed scatter with pos_embed.
template<int BN, int MODE, bool GELU, int KS>
__global__ __launch_bounds__(256) void gemm_bt(
    const u16* __restrict__ A, const u16* __restrict__ Bt,
    const float* __restrict__ bias,
    float* __restrict__ Cf, u16* __restrict__ Cb,
    int M, int N, int K, const float* __restrict__ pos, long pstride)
{
  constexpr int FJ = BN / 32;
  constexpr int LTOT = 4 + FJ;
  __shared__ vi4 As[2][1024];
  __shared__ vi4 Bs[2][BN * 8];

  // bijective XCD-aware swizzle (m204)
  int gx = gridDim.x, gy = gridDim.y;
  int nwg = gx * gy * (int)gridDim.z;
  int orig = blockIdx.x + gx * (blockIdx.y + gy * blockIdx.z);
  int qq = nwg >> 3, rr = nwg & 7;
  int xcd = orig & 7, off = orig >> 3;
  int id = (xcd < rr) ? xcd * (qq + 1) + off : rr * (qq + 1) + (xcd - rr) * qq + off;
  int bx = id % gx, rest = id / gx, by = rest % gy, bz = rest / gy;

  int tid = threadIdx.x, lane = tid & 63, wid = tid >> 6;
  int wm = wid >> 1, wn = wid & 1;
  int m0 = by * 128, n0 = bx * BN;
  int kBeg = (K / KS) * bz;
  int nT = (K / KS) >> 6;
  f32x4 acc[4][FJ] = {};

  auto STAGE = [&](int buf, int kk) {
    #pragma unroll
    for (int r = 0; r < 4; ++r) {
      int flat = r * 256 + tid;
      int row = flat >> 3, c = flat & 7;
      int cs = c ^ (row & 7);
      gload_lds16(A + (long)(m0 + row) * K + kk + cs * 8, &As[buf][r * 256 + wid * 64]);
    }
    #pragma unroll
    for (int r = 0; r < FJ; ++r) {
      int flat = r * 256 + tid;
      int row = flat >> 3, c = flat & 7;
      int cs = c ^ (row & 7);
      gload_lds16(Bt + (long)(n0 + row) * K + kk + cs * 8, &Bs[buf][r * 256 + wid * 64]);
    }
  };

  STAGE(0, kBeg);
  int cur = 0;
  for (int t = 0; t < nT; ++t) {
    if (t + 1 < nT) {
      STAGE(cur ^ 1, kBeg + (t + 1) * 64);
      asm volatile("s_waitcnt vmcnt(%0)" :: "i"(LTOT) : "memory");
    } else {
      asm volatile("s_waitcnt vmcnt(0)" ::: "memory");
    }
    __builtin_amdgcn_s_barrier();
    int cg = lane >> 4, l15 = lane & 15;
    #pragma unroll
    for (int ks = 0; ks < 2; ++ks) {
      bf16x8 af[4], bfr[FJ];
      #pragma unroll
      for (int i = 0; i < 4; ++i) {
        int ra = wm * 64 + i * 16 + l15;
        af[i] = __builtin_bit_cast(bf16x8, As[cur][ra * 8 + ((ks * 4 + cg) ^ (ra & 7))]);
      }
      #pragma unroll
      for (int j = 0; j < FJ; ++j) {
        int rb = wn * (BN / 2) + j * 16 + l15;
        bfr[j] = __builtin_bit_cast(bf16x8, Bs[cur][rb * 8 + ((ks * 4 + cg) ^ (rb & 7))]);
      }
      #pragma unroll
      for (int i = 0; i < 4; ++i)
        #pragma unroll
        for (int j = 0; j < FJ; ++j)
          acc[i][j] = __builtin_amdgcn_mfma_f32_16x16x32_bf16(af[i], bfr[j], acc[i][j], 0, 0, 0);
    }
    __builtin_amdgcn_s_barrier();
    cur ^= 1;
  }

  int cg = lane >> 4, l15 = lane & 15;
  float* Cfz = (MODE == 2 && KS > 1) ? Cf + (long)bz * pstride : Cf;
  u16* Cbz = (MODE == 4 && KS > 1) ? Cb + (long)bz * pstride : Cb;
  #pragma unroll
  for (int i = 0; i < 4; ++i) {
    #pragma unroll
    for (int j = 0; j < FJ; ++j) {
      int col = n0 + wn * (BN / 2) + j * 16 + l15;
      float bv = bias ? bias[col] : 0.f;
      #pragma unroll
      for (int r = 0; r < 4; ++r) {
        int row = m0 + wm * 64 + i * 16 + cg * 4 + r;
        if (row < M) {
          float v = acc[i][j][r];
          if (KS == 1 || bz == 0) v += bv;
          if (GELU) v = v / (1.f + __expf(-1.702f * v));
          if (MODE == 0) Cb[(long)row * N + col] = f2bf(v);
          else if (MODE == 2) Cfz[(long)row * N + col] = v;
          else if (MODE == 4) Cbz[(long)row * N + col] = f2bf(v);
          else {
            int hw = row % 196;
            int xr = (row / 196) * 223 + 27 + hw;
            Cf[(long)xr * 768 + col] = v + pos[(27 + hw) * 768 + col];
          }
        }
      }
    }
  }
}

// ---------------- attention (swapped QK^T, in-register P, tr_b16 V reads) ----------------
// grid (2 qhalves, 12 heads, 16 batch); block 256. XCD-pair swizzle keeps both qg of one
// (h,b) on one XCD. Q loads hoisted before the staging barrier (latency hidden).
__global__ __launch_bounds__(256) void attn_kernel(
    const u16* __restrict__ QKV, const int* __restrict__ aom, u16* __restrict__ O)
{
  __shared__ vi4 Kl[224 * 8];   // K row-major [key][8 chunks], chunk XOR (key&7)
  __shared__ vi4 Vl[224 * 8];   // V subtiled [sk][sd^(sk&3)][4 keys][16 d] (128B subtiles)
  __shared__ int ml[196];
  int tid = threadIdx.x, lane = tid & 63, wid = tid >> 6;
  // m204 swizzle, nwg = 384 (384 % 8 == 0): id = (orig&7)*48 + orig>>3
  int orig = blockIdx.x + 2 * (blockIdx.y + 12 * blockIdx.z);
  int id = (orig & 7) * 48 + (orig >> 3);
  int qg = id & 1, h = (id >> 1) % 12, b = id / 24;
  long rowbase = (long)b * 223;
  #pragma unroll
  for (int it = 0; it < 7; ++it) {
    int flat = it * 256 + tid;
    int s = flat >> 3, c = flat & 7;
    int cs = c ^ (s & 7);
    gload_lds16(QKV + (rowbase + s) * 2304 + 768 + h * 64 + cs * 8, &Kl[it * 256 + wid * 64]);
  }
  #pragma unroll
  for (int it = 0; it < 7; ++it) {
    int u = it * 256 + tid;
    int slin = u >> 3, inner = u & 7;
    int sk = slin >> 2, sdp = slin & 3;
    int s = sk * 4 + (inner >> 1);
    int c = ((sdp ^ (sk & 3)) << 1) | (inner & 1);
    gload_lds16(QKV + (rowbase + s) * 2304 + 1536 + h * 64 + c * 8, &Vl[it * 256 + wid * 64]);
  }
  for (int i = tid; i < 196; i += 256) ml[i] = aom[b * 196 + i];

  // Q loads hoisted: issued before the staging drain, latency overlapped
  int l15 = lane & 15, cg = lane >> 4;
  bf16x8 aq[2][2];
  #pragma unroll
  for (int rep = 0; rep < 2; ++rep) {
    int fo = wid * 2 + rep;
    int qf = qg * 7 + (fo < 7 ? fo : 6);
    int arow = qf * 16 + l15; if (arow > 222) arow = 222;
    const u16* qb = QKV + (rowbase + arow) * 2304 + h * 64;
    aq[rep][0] = ld_bf8(qb + cg * 8);
    aq[rep][1] = ld_bf8(qb + 32 + cg * 8);
  }
  __syncthreads();

  unsigned vbase = lds_off(Vl);
  #pragma unroll
  for (int rep = 0; rep < 2; ++rep) {
    int fo = wid * 2 + rep;
    if (fo >= 7) break;
    int qf = qg * 7 + fo;
    int q0 = qf * 16;

    f32x4 sc[14];
    #pragma unroll
    for (int kf = 0; kf < 14; ++kf) {
      int key = kf * 16 + l15;
      f32x4 a = {0.f, 0.f, 0.f, 0.f};
      bf16x8 bk0 = __builtin_bit_cast(bf16x8, Kl[key * 8 + (cg ^ (key & 7))]);
      bf16x8 bk1 = __builtin_bit_cast(bf16x8, Kl[key * 8 + ((4 + cg) ^ (key & 7))]);
      a = __builtin_amdgcn_mfma_f32_16x16x32_bf16(bk0, aq[rep][0], a, 0, 0, 0);
      a = __builtin_amdgcn_mfma_f32_16x16x32_bf16(bk1, aq[rep][1], a, 0, 0, 0);
      sc[kf] = a;
    }
    int q = q0 + l15;
    float mx = -3.4e38f;
    #pragma unroll
    for (int kf = 0; kf < 14; ++kf) {
      #pragma unroll
      for (int r = 0; r < 4; ++r) {
        int key = kf * 16 + cg * 4 + r;
        float mval;
        if (key >= 223) mval = NEGV;
        else if (q >= 27) mval = (key < 27) ? NEGV : 0.f;
        else if (key < 27) mval = (key == q) ? 0.f : NEGV;
        else mval = (ml[key - 27] == q) ? 0.f : NEGV;
        float sv = sc[kf][r] * 0.125f + mval;
        sc[kf][r] = sv;
        mx = fmaxf(mx, sv);
      }
    }
    mx = fmaxf(mx, __shfl_xor(mx, 16));
    mx = fmaxf(mx, __shfl_xor(mx, 32));
    float sum = 0.f;
    #pragma unroll
    for (int kf = 0; kf < 14; ++kf) {
      #pragma unroll
      for (int r = 0; r < 4; ++r) {
        float e = __expf(sc[kf][r] - mx);
        sc[kf][r] = e; sum += e;
      }
    }
    sum += __shfl_xor(sum, 16);
    sum += __shfl_xor(sum, 32);
    float inv = 1.f / sum;
    unsigned plo[14], phi[14];
    #pragma unroll
    for (int kf = 0; kf < 14; ++kf) {
      plo[kf] = (unsigned)f2bf(sc[kf][0] * inv) | ((unsigned)f2bf(sc[kf][1] * inv) << 16);
      phi[kf] = (unsigned)f2bf(sc[kf][2] * inv) | ((unsigned)f2bf(sc[kf][3] * inv) << 16);
    }
    f32x4 oacc[4] = {};
    #pragma unroll
    for (int ks = 0; ks < 7; ++ks) {
      uint2v vr[4][2];
      int sk0 = ks * 8 + cg * 2, sk1 = sk0 + 1;
      #pragma unroll
      for (int nf = 0; nf < 4; ++nf) {
        vr[nf][0] = ds_tr16(vbase + (unsigned)(((sk0 * 4 + (nf ^ (sk0 & 3))) << 7) + l15 * 8));
        vr[nf][1] = ds_tr16(vbase + (unsigned)(((sk1 * 4 + (nf ^ (sk1 & 3))) << 7) + l15 * 8));
      }
      int src0 = ((cg & 1) << 5) + l15, src1 = src0 + 16;
      int lo0 = __shfl((int)plo[2 * ks], src0),     hi0 = __shfl((int)phi[2 * ks], src0);
      int lo1 = __shfl((int)plo[2 * ks + 1], src0), hi1 = __shfl((int)phi[2 * ks + 1], src0);
      int lo0b = __shfl((int)plo[2 * ks], src1),     hi0b = __shfl((int)phi[2 * ks], src1);
      int lo1b = __shfl((int)plo[2 * ks + 1], src1), hi1b = __shfl((int)phi[2 * ks + 1], src1);
      bool hg = (cg >> 1) & 1;
      vi4 paw = { hg ? lo1 : lo0, hg ? hi1 : hi0, hg ? lo1b : lo0b, hg ? hi1b : hi0b };
      bf16x8 pa = __builtin_bit_cast(bf16x8, paw);
      asm volatile("s_waitcnt lgkmcnt(0)" ::: "memory");
      __builtin_amdgcn_sched_barrier(0);
      #pragma unroll
      for (int nf = 0; nf < 4; ++nf) {
        vi4 bw = { (int)vr[nf][0][0], (int)vr[nf][0][1], (int)vr[nf][1][0], (int)vr[nf][1][1] };
        oacc[nf] = __builtin_amdgcn_mfma_f32_16x16x32_bf16(pa, __builtin_bit_cast(bf16x8, bw), oacc[nf], 0, 0, 0);
      }
    }
    #pragma unroll
    for (int nf = 0; nf < 4; ++nf) {
      int d = h * 64 + nf * 16 + l15;
      #pragma unroll
      for (int r = 0; r < 4; ++r) {
        int qo = q0 + cg * 4 + r;
        if (qo < 223) O[(rowbase + qo) * 768 + d] = f2bf(oacc[nf][r]);
      }
    }
  }
}

// ---------------- fused residual + LayerNorm: one WAVE per row ----------------
// NADD=2: xnew = X + P0 + P1 (partials, bf16 if PBF16, P1 at +ps elements);
// optionally write xnew back; H = LN(xnew).
template<int NADD, bool PBF16, bool MAP27, bool WRITEX>
__global__ __launch_bounds__(256) void ln_kernel(
    const float* __restrict__ X, const void* __restrict__ P, long ps,
    float* __restrict__ Xout, u16* __restrict__ Hb,
    const float* __restrict__ w, const float* __restrict__ bb, int nrows)
{
  int row = blockIdx.x * 4 + (threadIdx.x >> 6);
  if (row >= nrows) return;
  int xr = MAP27 ? (row / 27) * 223 + (row % 27) : row;
  int l = threadIdx.x & 63;
  const float4* xp = (const float4*)(X + (long)xr * 768);
  float4 a = xp[l], c = xp[l + 64], d = xp[l + 128];
  if (NADD == 2) {
    if (PBF16) {
      const u16* pb = (const u16*)P;
      const u16* p0 = pb + (long)xr * 768;
      const u16* p1 = pb + ps + (long)xr * 768;
      short4v a0 = *(const short4v*)(p0 + l * 4);
      short4v a1 = *(const short4v*)(p0 + 256 + l * 4);
      short4v a2 = *(const short4v*)(p0 + 512 + l * 4);
      short4v e0 = *(const short4v*)(p1 + l * 4);
      short4v e1 = *(const short4v*)(p1 + 256 + l * 4);
      short4v e2 = *(const short4v*)(p1 + 512 + l * 4);
      a.x += b2f((u16)a0[0]) + b2f((u16)e0[0]); a.y += b2f((u16)a0[1]) + b2f((u16)e0[1]);
      a.z += b2f((u16)a0[2]) + b2f((u16)e0[2]); a.w += b2f((u16)a0[3]) + b2f((u16)e0[3]);
      c.x += b2f((u16)a1[0]) + b2f((u16)e1[0]); c.y += b2f((u16)a1[1]) + b2f((u16)e1[1]);
      c.z += b2f((u16)a1[2]) + b2f((u16)e1[2]); c.w += b2f((u16)a1[3]) + b2f((u16)e1[3]);
      d.x += b2f((u16)a2[0]) + b2f((u16)e2[0]); d.y += b2f((u16)a2[1]) + b2f((u16)e2[1]);
      d.z += b2f((u16)a2[2]) + b2f((u16)e2[2]); d.w += b2f((u16)a2[3]) + b2f((u16)e2[3]);
    } else {
      const float* pf = (const float*)P;
      const float4* p0 = (const float4*)(pf + (long)xr * 768);
      const float4* p1 = (const float4*)(pf + ps + (long)xr * 768);
      float4 u0 = p0[l], u1 = p0[l + 64], u2 = p0[l + 128];
      float4 v0 = p1[l], v1 = p1[l + 64], v2 = p1[l + 128];
      a.x += u0.x + v0.x; a.y += u0.y + v0.y; a.z += u0.z + v0.z; a.w += u0.w + v0.w;
      c.x += u1.x + v1.x; c.y += u1.y + v1.y; c.z += u1.z + v1.z; c.w += u1.w + v1.w;
      d.x += u2.x + v2.x; d.y += u2.y + v2.y; d.z += u2.z + v2.z; d.w += u2.w + v2.w;
    }
  }
  if (WRITEX) {
    float4* xo = (float4*)(Xout + (long)xr * 768);
    xo[l] = a; xo[l + 64] = c; xo[l + 128] = d;
  }
  float s = a.x + a.y + a.z + a.w + c.x + c.y + c.z + c.w + d.x + d.y + d.z + d.w;
  #pragma unroll
  for (int t = 1; t < 64; t <<= 1) s += __shfl_xor(s, t);
  float mean = s * (1.f / 768.f);
  a.x -= mean; a.y -= mean; a.z -= mean; a.w -= mean;
  c.x -= mean; c.y -= mean; c.z -= mean; c.w -= mean;
  d.x -= mean; d.y -= mean; d.z -= mean; d.w -= mean;
  float q = a.x*a.x + a.y*a.y + a.z*a.z + a.w*a.w
          + c.x*c.x + c.y*c.y + c.z*c.z + c.w*c.w
          + d.x*d.x + d.y*d.y + d.z*d.z + d.w*d.w;
  #pragma unroll
  for (int t = 1; t < 64; t <<= 1) q += __shfl_xor(q, t);
  float rs = rsqrtf(q * (1.f / 768.f) + 1e-5f);
  const float4* wp = (const float4*)w;
  const float4* bp = (const float4*)bb;
  u16* out = Hb + (long)row * 768;
  float4 w0 = wp[l], w1 = wp[l + 64], w2 = wp[l + 128];
  float4 b0 = bp[l], b1 = bp[l + 64], b2 = bp[l + 128];
  short4v o;
  o[0] = (short)f2bf(a.x * rs * w0.x + b0.x); o[1] = (short)f2bf(a.y * rs * w0.y + b0.y);
  o[2] = (short)f2bf(a.z * rs * w0.z + b0.z); o[3] = (short)f2bf(a.w * rs * w0.w + b0.w);
  *(short4v*)(out + l * 4) = o;
  o[0] = (short)f2bf(c.x * rs * w1.x + b1.x); o[1] = (short)f2bf(c.y * rs * w1.y + b1.y);
  o[2] = (short)f2bf(c.z * rs * w1.z + b1.z); o[3] = (short)f2bf(c.w * rs * w1.w + b1.w);
  *(short4v*)(out + 256 + l * 4) = o;
  o[0] = (short)f2bf(d.x * rs * w2.x + b2.x); o[1] = (short)f2bf(d.y * rs * w2.y + b2.y);
  o[2] = (short)f2bf(d.z * rs * w2.z + b2.z); o[3] = (short)f2bf(d.w * rs * w2.w + b2.w);
  *(short4v*)(out + 512 + l * 4) = o;
}

// ---------------- weight transpose + f32->bf16: W[K][N] -> WT[N][K], batched over z ----------------
__global__ __launch_bounds__(256) void transpose_w(
    const float* __restrict__ W, u16* __restrict__ WT, int K, int N, long sW, long sT)
{
  __shared__ float t[64][65];
  int z = blockIdx.z;
  W += (long)z * sW; WT += (long)z * sT;
  int n0 = blockIdx.x * 64, k0 = blockIdx.y * 64;
  #pragma unroll
  for (int i = 0; i < 4; ++i) {
    int flat = i * 256 + threadIdx.x;
    int r = flat >> 4, c = (flat & 15) * 4;
    float4 v = *(const float4*)(W + (long)(k0 + r) * N + n0 + c);
    t[r][c] = v.x; t[r][c + 1] = v.y; t[r][c + 2] = v.z; t[r][c + 3] = v.w;
  }
  __syncthreads();
  #pragma unroll
  for (int i = 0; i < 8; ++i) {
    int flat = i * 256 + threadIdx.x;
    int rn = flat >> 5, ck = (flat & 31) * 2;
    unsigned val = (unsigned)f2bf(t[ck][rn]) | ((unsigned)f2bf(t[ck + 1][rn]) << 16);
    *(unsigned*)(WT + (long)(n0 + rn) * K + k0 + ck) = val;
  }
}

__global__ void convert_bf16(const float* __restrict__ src, u16* __restrict__ dst, int n4) {
  int i = blockIdx.x * 256 + threadIdx.x;
  if (i < n4) {
    float4 v = ((const float4*)src)[i];
    short4v o;
    o[0] = (short)f2bf(v.x); o[1] = (short)f2bf(v.y); o[2] = (short)f2bf(v.z); o[3] = (short)f2bf(v.w);
    *(short4v*)(dst + i * 4) = o;
  }
}

__global__ __launch_bounds__(192) void patch_extract(const float* __restrict__ img, u16* __restrict__ Xp) {
  int row = blockIdx.x;
  int t = threadIdx.x;
  int pair = t >> 2, part = t & 3;
  int cch = pair >> 4, kh = pair & 15;
  int b = row / 196, hw = row % 196, gh = hw / 14, gw = hw % 14;
  float4 v = *(const float4*)(img + ((long)(b * 3 + cch) * 224 + gh * 16 + kh) * 224 + gw * 16 + part * 4);
  short4v o;
  o[0] = (short)f2bf(v.x); o[1] = (short)f2bf(v.y); o[2] = (short)f2bf(v.z); o[3] = (short)f2bf(v.w);
  *(short4v*)(Xp + (long)row * 768 + pair * 16 + part * 4) = o;
}

__global__ void cls_pos_fill(const float* __restrict__ cls, const float* __restrict__ pos, float* __restrict__ x) {
  int i = blockIdx.x * 256 + threadIdx.x;
  if (i >= 16 * 27 * 768) return;
  int d = i % 768, t = i / 768, b = t / 27, s = t % 27;
  x[((long)b * 223 + s) * 768 + d] = cls[s * 768 + d] + pos[s * 768 + d];
}

// fused: obj = P0+P1 (head split-K partials, f32); pid = (obj/|obj|)·(sents/|sents|)
__global__ __launch_bounds__(256) void norm_dot(
    const float* __restrict__ objp, long ps, const float* __restrict__ sents,
    float* __restrict__ pid)
{
  __shared__ float sb[12];
  int r = blockIdx.x, t = threadIdx.x, b = r / 27;
  long base = (long)r * 512;
  float v0 = objp[base + t] + objp[ps + base + t];
  float v1 = objp[base + t + 256] + objp[ps + base + t + 256];
  float w0 = sents[b * 512 + t], w1 = sents[b * 512 + t + 256];
  float q = v0 * v0 + v1 * v1;
  float dt = v0 * w0 + v1 * w1;
  float sw = w0 * w0 + w1 * w1;
  #pragma unroll
  for (int d = 1; d < 64; d <<= 1) {
    q += __shfl_xor(q, d); dt += __shfl_xor(dt, d); sw += __shfl_xor(sw, d);
  }
  if ((t & 63) == 0) { sb[t >> 6] = q; sb[4 + (t >> 6)] = dt; sb[8 + (t >> 6)] = sw; }
  __syncthreads();
  if (t == 0)
    pid[r] = (sb[4] + sb[5] + sb[6] + sb[7])
           * rsqrtf(sb[0] + sb[1] + sb[2] + sb[3])
           * rsqrtf(sb[8] + sb[9] + sb[10] + sb[11]);
}

__global__ void gather_pred(const int* __restrict__ om, const float* __restrict__ pid, float* __restrict__ out) {
  int i = blockIdx.x * 256 + threadIdx.x;
  if (i >= 16 * 224 * 224) return;
  int b = i / (224 * 224);
  out[i] = pid[b * 27 + om[i]];
}

extern "C" void kernel_launch(void* const* d_in, const int* in_sizes, int n_in,
                              void* d_out, int out_size, void* d_ws, size_t ws_size,
                              hipStream_t stream) {
  const float* img     = (const float*)d_in[0];
  const float* sents   = (const float*)d_in[1];
  const int*   aom     = (const int*)d_in[2];
  const int*   omask   = (const int*)d_in[3];
  const float* cls     = (const float*)d_in[4];
  const float* patch_w = (const float*)d_in[5];
  const float* patch_b = (const float*)d_in[6];
  const float* pos     = (const float*)d_in[7];
  const float* ln1w    = (const float*)d_in[8];
  const float* ln1b    = (const float*)d_in[9];
  const float* qkvw    = (const float*)d_in[10];
  const float* qkvb    = (const float*)d_in[11];
  const float* outw    = (const float*)d_in[12];
  const float* outb    = (const float*)d_in[13];
  const float* ln2w    = (const float*)d_in[14];
  const float* ln2b    = (const float*)d_in[15];
  const float* m1w     = (const float*)d_in[16];
  const float* m1b     = (const float*)d_in[17];
  const float* m2w     = (const float*)d_in[18];
  const float* m2b     = (const float*)d_in[19];
  const float* lnpw    = (const float*)d_in[20];
  const float* lnpb    = (const float*)d_in[21];
  const float* projw   = (const float*)d_in[22];

  char* p = (char*)d_ws;
  auto alloc = [&](size_t bytes) { char* r = p; p += (bytes + 255) & ~(size_t)255; return r; };
  const long PSH = 3584l * 768;   // bf16 partial stride (elements)
  const long OPS = 432l * 512;    // head f32 partial stride
  float* x   = (float*)alloc(3568ul * 768 * 4);
  u16* H     = (u16*)alloc(3584ul * 768 * 2);
  u16* QKV   = (u16*)alloc(3584ul * 2304 * 2);
  u16* Obuf  = (u16*)alloc(3584ul * 768 * 2);
  u16* G     = (u16*)alloc(3584ul * 3072 * 2);
  u16* Yb    = (u16*)alloc((size_t)PSH * 2 * 2);  // out-proj bf16 partials (2 halves)
  u16* Mb    = (u16*)alloc((size_t)PSH * 2 * 2);  // MLP2 bf16 partials
  u16* PWc   = (u16*)alloc(768ul * 768 * 2);
  u16* PrT   = (u16*)alloc(512ul * 768 * 2);
  float* obj = (float*)alloc((size_t)OPS * 2 * 4);
  float* pid = (float*)alloc(432ul * 4);

  const size_t wlayer = (2304ul * 768 + 768ul * 768 + 3072ul * 768 + 768ul * 3072) * 2;
  size_t used = (size_t)(p - (char*)d_ws);
  int nw = (ws_size >= used + 12 * wlayer + 65536) ? 12 : 1;
  const long sQ = 2304l * 768, sO = 768l * 768, s1 = 768l * 3072, s2 = 3072l * 768;
  u16* WqT = (u16*)alloc((size_t)sQ * 2 * nw);
  u16* WoT = (u16*)alloc((size_t)sO * 2 * nw);
  u16* W1T = (u16*)alloc((size_t)s1 * 2 * nw);
  u16* W2T = (u16*)alloc((size_t)s2 * 2 * nw);

  convert_bf16<<<576, 256, 0, stream>>>(patch_w, PWc, 147456);
  transpose_w<<<dim3(8, 12, 1), 256, 0, stream>>>(projw, PrT, 768, 512, 0, 0);
  if (nw == 12) {
    transpose_w<<<dim3(36, 12, 12), 256, 0, stream>>>(qkvw, WqT, 768, 2304, sQ, sQ);
    transpose_w<<<dim3(12, 12, 12), 256, 0, stream>>>(outw, WoT, 768, 768, sO, sO);
    transpose_w<<<dim3(48, 12, 12), 256, 0, stream>>>(m1w, W1T, 768, 3072, s1, s1);
    transpose_w<<<dim3(12, 48, 12), 256, 0, stream>>>(m2w, W2T, 3072, 768, s2, s2);
  }
  patch_extract<<<3136, 192, 0, stream>>>(img, H);
  cls_pos_fill<<<1296, 256, 0, stream>>>(cls, pos, x);
  gemm_bt<64, 3, false, 1><<<dim3(12, 25), 256, 0, stream>>>(H, PWc, patch_b, x, nullptr, 3136, 768, 768, pos, 0);

  for (int l = 0; l < 12; ++l) {
    u16 *wq, *wo, *w1, *w2;
    if (nw == 12) { wq = WqT + (long)l * sQ; wo = WoT + (long)l * sO; w1 = W1T + (long)l * s1; w2 = W2T + (long)l * s2; }
    else {
      wq = WqT; wo = WoT; w1 = W1T; w2 = W2T;
      transpose_w<<<dim3(36, 12, 1), 256, 0, stream>>>(qkvw + (long)l * sQ, wq, 768, 2304, 0, 0);
      transpose_w<<<dim3(12, 12, 1), 256, 0, stream>>>(outw + (long)l * sO, wo, 768, 768, 0, 0);
      transpose_w<<<dim3(48, 12, 1), 256, 0, stream>>>(m1w + (long)l * s1, w1, 768, 3072, 0, 0);
      transpose_w<<<dim3(12, 48, 1), 256, 0, stream>>>(m2w + (long)l * s2, w2, 3072, 768, 0, 0);
    }
    if (l == 0)
      ln_kernel<0, false, false, false><<<892, 256, 0, stream>>>(x, nullptr, 0, nullptr, H, ln1w, ln1b, 3568);
    else
      ln_kernel<2, true, false, true><<<892, 256, 0, stream>>>(x, Mb, PSH, x, H, ln1w + l * 768, ln1b + l * 768, 3568);
    gemm_bt<128, 0, false, 1><<<dim3(18, 28), 256, 0, stream>>>(H, wq, qkvb + l * 2304, nullptr, QKV, 3568, 2304, 768, nullptr, 0);
    attn_kernel<<<dim3(2, 12, 16), 256, 0, stream>>>(QKV, aom, Obuf);
    gemm_bt<64, 4, false, 2><<<dim3(12, 28, 2), 256, 0, stream>>>(Obuf, wo, outb + l * 768, nullptr, Yb, 3568, 768, 768, nullptr, PSH);
    ln_kernel<2, true, false, true><<<892, 256, 0, stream>>>(x, Yb, PSH, x, H, ln2w + l * 768, ln2b + l * 768, 3568);
    gemm_bt<128, 0, true, 1><<<dim3(24, 28), 256, 0, stream>>>(H, w1, m1b + l * 3072, nullptr, G, 3568, 3072, 768, nullptr, 0);
    gemm_bt<64, 4, false, 2><<<dim3(12, 28, 2), 256, 0, stream>>>(G, w2, m2b + l * 768, nullptr, Mb, 3568, 768, 3072, nullptr, PSH);
  }

  ln_kernel<2, true, true, false><<<108, 256, 0, stream>>>(x, Mb, PSH, nullptr, H, lnpw, lnpb, 432);
  gemm_bt<64, 2, false, 2><<<dim3(8, 4, 2), 256, 0, stream>>>(H, PrT, nullptr, obj, nullptr, 432, 512, 768, nullptr, OPS);
  norm_dot<<<432, 256, 0, stream>>>(obj, OPS, sents, pid);
  gather_pred<<<3136, 256, 0, stream>>>(omask, pid, (float*)d_out);
}

// Round 13
// 2044.465 us; speedup vs baseline: 1.1551x; 1.0115x over previous
//
#include <hip/hip_runtime.h>

#define DEV __device__ __forceinline__

typedef short bf16x8 __attribute__((ext_vector_type(8)));
typedef float f32x4 __attribute__((ext_vector_type(4)));
typedef int vi4 __attribute__((ext_vector_type(4)));
typedef unsigned uint2v __attribute__((ext_vector_type(2)));
typedef unsigned short u16;
typedef short short4v __attribute__((ext_vector_type(4)));

#define NEGV -1000000000.0f

DEV u16 f2bf(float f) {
  union { float f; unsigned u; } v; v.f = f;
  unsigned r = v.u + 0x7FFFu + ((v.u >> 16) & 1u);
  return (u16)(r >> 16);
}

DEV float b2f(u16 s) {
  union { unsigned u; float f; } v; v.u = ((unsigned)s) << 16;
  return v.f;
}

DEV bf16x8 ld_bf8(const u16* p) {
  vi4 v = *(const vi4*)p;
  return __builtin_bit_cast(bf16x8, v);
}

DEV void gload_lds16(const u16* g, vi4* l) {
  __builtin_amdgcn_global_load_lds((const __attribute__((address_space(1))) void*)g,
                                   (__attribute__((address_space(3))) void*)l, 16, 0, 0);
}

DEV unsigned lds_off(const void* p) {
  return (unsigned)(unsigned long long)(const __attribute__((address_space(3))) void*)p;
}

DEV uint2v ds_tr16(unsigned byteaddr) {
  uint2v r;
  asm volatile("ds_read_b64_tr_b16 %0, %1" : "=v"(r) : "v"(byteaddr));
  return r;
}

// ---------------- generic GEMM: C[M,N] = A[Mpad,K](bf16) @ Bt[N,K](bf16)^T ----------------
// BK=64, 2-buffer pipeline, counted vmcnt. A rows PADDED to mult of 128.
// MODE 0: Cb = bf16(acc+bias); MODE 2: Cf[+bz*pstride] = acc (+bias@z0) f32 split-K partials;
// MODE 4: Cb[+bz*pstride] = bf16(acc (+bias@z0)) bf16 split-K partials (summed by fused LN);
// MODE 3: patch-embed scatter with pos_embed.
template<int BN, int MODE, bool GELU, int KS>
__global__ __launch_bounds__(256) void gemm_bt(
    const u16* __restrict__ A, const u16* __restrict__ Bt,
    const float* __restrict__ bias,
    float* __restrict__ Cf, u16* __restrict__ Cb,
    int M, int N, int K, const float* __restrict__ pos, long pstride)
{
  constexpr int FJ = BN / 32;
  constexpr int LTOT = 4 + FJ;
  __shared__ vi4 As[2][1024];
  __shared__ vi4 Bs[2][BN * 8];

  // bijective XCD-aware swizzle (m204)
  int gx = gridDim.x, gy = gridDim.y;
  int nwg = gx * gy * (int)gridDim.z;
  int orig = blockIdx.x + gx * (blockIdx.y + gy * blockIdx.z);
  int qq = nwg >> 3, rr = nwg & 7;
  int xcd = orig & 7, off = orig >> 3;
  int id = (xcd < rr) ? xcd * (qq + 1) + off : rr * (qq + 1) + (xcd - rr) * qq + off;
  int bx = id % gx, rest = id / gx, by = rest % gy, bz = rest / gy;

  int tid = threadIdx.x, lane = tid & 63, wid = tid >> 6;
  int wm = wid >> 1, wn = wid & 1;
  int m0 = by * 128, n0 = bx * BN;
  int kBeg = (K / KS) * bz;
  int nT = (K / KS) >> 6;
  f32x4 acc[4][FJ] = {};

  auto STAGE = [&](int buf, int kk) {
    #pragma unroll
    for (int r = 0; r < 4; ++r) {
      int flat = r * 256 + tid;
      int row = flat >> 3, c = flat & 7;
      int cs = c ^ (row & 7);
      gload_lds16(A + (long)(m0 + row) * K + kk + cs * 8, &As[buf][r * 256 + wid * 64]);
    }
    #pragma unroll
    for (int r = 0; r < FJ; ++r) {
      int flat = r * 256 + tid;
      int row = flat >> 3, c = flat & 7;
      int cs = c ^ (row & 7);
      gload_lds16(Bt + (long)(n0 + row) * K + kk + cs * 8, &Bs[buf][r * 256 + wid * 64]);
    }
  };

  STAGE(0, kBeg);
  int cur = 0;
  for (int t = 0; t < nT; ++t) {
    if (t + 1 < nT) {
      STAGE(cur ^ 1, kBeg + (t + 1) * 64);
      asm volatile("s_waitcnt vmcnt(%0)" :: "i"(LTOT) : "memory");
    } else {
      asm volatile("s_waitcnt vmcnt(0)" ::: "memory");
    }
    __builtin_amdgcn_s_barrier();
    int cg = lane >> 4, l15 = lane & 15;
    #pragma unroll
    for (int ks = 0; ks < 2; ++ks) {
      bf16x8 af[4], bfr[FJ];
      #pragma unroll
      for (int i = 0; i < 4; ++i) {
        int ra = wm * 64 + i * 16 + l15;
        af[i] = __builtin_bit_cast(bf16x8, As[cur][ra * 8 + ((ks * 4 + cg) ^ (ra & 7))]);
      }
      #pragma unroll
      for (int j = 0; j < FJ; ++j) {
        int rb = wn * (BN / 2) + j * 16 + l15;
        bfr[j] = __builtin_bit_cast(bf16x8, Bs[cur][rb * 8 + ((ks * 4 + cg) ^ (rb & 7))]);
      }
      #pragma unroll
      for (int i = 0; i < 4; ++i)
        #pragma unroll
        for (int j = 0; j < FJ; ++j)
          acc[i][j] = __builtin_amdgcn_mfma_f32_16x16x32_bf16(af[i], bfr[j], acc[i][j], 0, 0, 0);
    }
    __builtin_amdgcn_s_barrier();
    cur ^= 1;
  }

  int cg = lane >> 4, l15 = lane & 15;
  float* Cfz = (MODE == 2 && KS > 1) ? Cf + (long)bz * pstride : Cf;
  u16* Cbz = (MODE == 4 && KS > 1) ? Cb + (long)bz * pstride : Cb;
  #pragma unroll
  for (int i = 0; i < 4; ++i) {
    #pragma unroll
    for (int j = 0; j < FJ; ++j) {
      int col = n0 + wn * (BN / 2) + j * 16 + l15;
      float bv = bias ? bias[col] : 0.f;
      #pragma unroll
      for (int r = 0; r < 4; ++r) {
        int row = m0 + wm * 64 + i * 16 + cg * 4 + r;
        if (row < M) {
          float v = acc[i][j][r];
          if (KS == 1 || bz == 0) v += bv;
          if (GELU) v = v / (1.f + __expf(-1.702f * v));
          if (MODE == 0) Cb[(long)row * N + col] = f2bf(v);
          else if (MODE == 2) Cfz[(long)row * N + col] = v;
          else if (MODE == 4) Cbz[(long)row * N + col] = f2bf(v);
          else {
            int hw = row % 196;
            int xr = (row / 196) * 223 + 27 + hw;
            Cf[(long)xr * 768 + col] = v + pos[(27 + hw) * 768 + col];
          }
        }
      }
    }
  }
}

// ---------------- attention (swapped QK^T, in-register P, tr_b16 V reads) ----------------
// grid (12 heads, 16 batch); block 512 = 8 waves, each wave up to 2 q-frags of 16 rows.
// K/V/mask staged ONCE per (h,b) (was twice with the 2-qhalf grid).
__global__ __launch_bounds__(512) void attn_kernel(
    const u16* __restrict__ QKV, const int* __restrict__ aom, u16* __restrict__ O)
{
  __shared__ vi4 Kl[224 * 8];   // K row-major [key][8 chunks], chunk XOR (key&7)
  __shared__ vi4 Vl[224 * 8];   // V subtiled [sk][sd^(sk&3)][4 keys][16 d] (128B subtiles)
  __shared__ int ml[196];
  int tid = threadIdx.x, lane = tid & 63, wid = tid >> 6;  // wid 0..7
  int h = blockIdx.x, b = blockIdx.y;
  long rowbase = (long)b * 223;
  // K staging: 1792 slots over 512 threads (wave-uniform tail predicate: 1792 = 28 waves)
  #pragma unroll
  for (int it = 0; it < 4; ++it) {
    int flat = it * 512 + tid;
    if (flat < 1792) {
      int s = flat >> 3, c = flat & 7;
      int cs = c ^ (s & 7);
      gload_lds16(QKV + (rowbase + s) * 2304 + 768 + h * 64 + cs * 8, &Kl[it * 512 + wid * 64]);
    }
  }
  // V staging: dest slot u -> (s, c) inverted through the subtile+swizzle map
  #pragma unroll
  for (int it = 0; it < 4; ++it) {
    int u = it * 512 + tid;
    if (u < 1792) {
      int slin = u >> 3, inner = u & 7;
      int sk = slin >> 2, sdp = slin & 3;
      int s = sk * 4 + (inner >> 1);
      int c = ((sdp ^ (sk & 3)) << 1) | (inner & 1);
      gload_lds16(QKV + (rowbase + s) * 2304 + 1536 + h * 64 + c * 8, &Vl[it * 512 + wid * 64]);
    }
  }
  for (int i = tid; i < 196; i += 512) ml[i] = aom[b * 196 + i];

  // Q loads hoisted: issued before the staging drain, latency overlapped
  int l15 = lane & 15, cg = lane >> 4;
  bf16x8 aq[2][2];
  #pragma unroll
  for (int rep = 0; rep < 2; ++rep) {
    int fo = wid * 2 + rep;
    int qf = (fo < 14) ? fo : 13;
    int arow = qf * 16 + l15; if (arow > 222) arow = 222;
    const u16* qb = QKV + (rowbase + arow) * 2304 + h * 64;
    aq[rep][0] = ld_bf8(qb + cg * 8);
    aq[rep][1] = ld_bf8(qb + 32 + cg * 8);
  }
  __syncthreads();

  unsigned vbase = lds_off(Vl);
  #pragma unroll
  for (int rep = 0; rep < 2; ++rep) {
    int fo = wid * 2 + rep;
    if (fo >= 14) break;
    int q0 = fo * 16;

    f32x4 sc[14];
    #pragma unroll
    for (int kf = 0; kf < 14; ++kf) {
      int key = kf * 16 + l15;
      f32x4 a = {0.f, 0.f, 0.f, 0.f};
      bf16x8 bk0 = __builtin_bit_cast(bf16x8, Kl[key * 8 + (cg ^ (key & 7))]);
      bf16x8 bk1 = __builtin_bit_cast(bf16x8, Kl[key * 8 + ((4 + cg) ^ (key & 7))]);
      a = __builtin_amdgcn_mfma_f32_16x16x32_bf16(bk0, aq[rep][0], a, 0, 0, 0);
      a = __builtin_amdgcn_mfma_f32_16x16x32_bf16(bk1, aq[rep][1], a, 0, 0, 0);
      sc[kf] = a;
    }
    int q = q0 + l15;
    float mx = -3.4e38f;
    #pragma unroll
    for (int kf = 0; kf < 14; ++kf) {
      #pragma unroll
      for (int r = 0; r < 4; ++r) {
        int key = kf * 16 + cg * 4 + r;
        float mval;
        if (key >= 223) mval = NEGV;
        else if (q >= 27) mval = (key < 27) ? NEGV : 0.f;
        else if (key < 27) mval = (key == q) ? 0.f : NEGV;
        else mval = (ml[key - 27] == q) ? 0.f : NEGV;
        float sv = sc[kf][r] * 0.125f + mval;
        sc[kf][r] = sv;
        mx = fmaxf(mx, sv);
      }
    }
    mx = fmaxf(mx, __shfl_xor(mx, 16));
    mx = fmaxf(mx, __shfl_xor(mx, 32));
    float sum = 0.f;
    #pragma unroll
    for (int kf = 0; kf < 14; ++kf) {
      #pragma unroll
      for (int r = 0; r < 4; ++r) {
        float e = __expf(sc[kf][r] - mx);
        sc[kf][r] = e; sum += e;
      }
    }
    sum += __shfl_xor(sum, 16);
    sum += __shfl_xor(sum, 32);
    float inv = 1.f / sum;
    unsigned plo[14], phi[14];
    #pragma unroll
    for (int kf = 0; kf < 14; ++kf) {
      plo[kf] = (unsigned)f2bf(sc[kf][0] * inv) | ((unsigned)f2bf(sc[kf][1] * inv) << 16);
      phi[kf] = (unsigned)f2bf(sc[kf][2] * inv) | ((unsigned)f2bf(sc[kf][3] * inv) << 16);
    }
    f32x4 oacc[4] = {};
    #pragma unroll
    for (int ks = 0; ks < 7; ++ks) {
      uint2v vr[4][2];
      int sk0 = ks * 8 + cg * 2, sk1 = sk0 + 1;
      #pragma unroll
      for (int nf = 0; nf < 4; ++nf) {
        vr[nf][0] = ds_tr16(vbase + (unsigned)(((sk0 * 4 + (nf ^ (sk0 & 3))) << 7) + l15 * 8));
        vr[nf][1] = ds_tr16(vbase + (unsigned)(((sk1 * 4 + (nf ^ (sk1 & 3))) << 7) + l15 * 8));
      }
      int src0 = ((cg & 1) << 5) + l15, src1 = src0 + 16;
      int lo0 = __shfl((int)plo[2 * ks], src0),     hi0 = __shfl((int)phi[2 * ks], src0);
      int lo1 = __shfl((int)plo[2 * ks + 1], src0), hi1 = __shfl((int)phi[2 * ks + 1], src0);
      int lo0b = __shfl((int)plo[2 * ks], src1),     hi0b = __shfl((int)phi[2 * ks], src1);
      int lo1b = __shfl((int)plo[2 * ks + 1], src1), hi1b = __shfl((int)phi[2 * ks + 1], src1);
      bool hg = (cg >> 1) & 1;
      vi4 paw = { hg ? lo1 : lo0, hg ? hi1 : hi0, hg ? lo1b : lo0b, hg ? hi1b : hi0b };
      bf16x8 pa = __builtin_bit_cast(bf16x8, paw);
      asm volatile("s_waitcnt lgkmcnt(0)" ::: "memory");
      __builtin_amdgcn_sched_barrier(0);
      #pragma unroll
      for (int nf = 0; nf < 4; ++nf) {
        vi4 bw = { (int)vr[nf][0][0], (int)vr[nf][0][1], (int)vr[nf][1][0], (int)vr[nf][1][1] };
        oacc[nf] = __builtin_amdgcn_mfma_f32_16x16x32_bf16(pa, __builtin_bit_cast(bf16x8, bw), oacc[nf], 0, 0, 0);
      }
    }
    #pragma unroll
    for (int nf = 0; nf < 4; ++nf) {
      int d = h * 64 + nf * 16 + l15;
      #pragma unroll
      for (int r = 0; r < 4; ++r) {
        int qo = q0 + cg * 4 + r;
        if (qo < 223) O[(rowbase + qo) * 768 + d] = f2bf(oacc[nf][r]);
      }
    }
  }
}

// ---------------- fused residual + LayerNorm: one WAVE per row ----------------
// NADD=2: xnew = X + P0 + P1 (partials, bf16 if PBF16, P1 at +ps elements);
// optionally write xnew back; H = LN(xnew).
template<int NADD, bool PBF16, bool MAP27, bool WRITEX>
__global__ __launch_bounds__(256) void ln_kernel(
    const float* __restrict__ X, const void* __restrict__ P, long ps,
    float* __restrict__ Xout, u16* __restrict__ Hb,
    const float* __restrict__ w, const float* __restrict__ bb, int nrows)
{
  int row = blockIdx.x * 4 + (threadIdx.x >> 6);
  if (row >= nrows) return;
  int xr = MAP27 ? (row / 27) * 223 + (row % 27) : row;
  int l = threadIdx.x & 63;
  const float4* xp = (const float4*)(X + (long)xr * 768);
  float4 a = xp[l], c = xp[l + 64], d = xp[l + 128];
  if (NADD == 2) {
    if (PBF16) {
      const u16* pb = (const u16*)P;
      const u16* p0 = pb + (long)xr * 768;
      const u16* p1 = pb + ps + (long)xr * 768;
      short4v a0 = *(const short4v*)(p0 + l * 4);
      short4v a1 = *(const short4v*)(p0 + 256 + l * 4);
      short4v a2 = *(const short4v*)(p0 + 512 + l * 4);
      short4v e0 = *(const short4v*)(p1 + l * 4);
      short4v e1 = *(const short4v*)(p1 + 256 + l * 4);
      short4v e2 = *(const short4v*)(p1 + 512 + l * 4);
      a.x += b2f((u16)a0[0]) + b2f((u16)e0[0]); a.y += b2f((u16)a0[1]) + b2f((u16)e0[1]);
      a.z += b2f((u16)a0[2]) + b2f((u16)e0[2]); a.w += b2f((u16)a0[3]) + b2f((u16)e0[3]);
      c.x += b2f((u16)a1[0]) + b2f((u16)e1[0]); c.y += b2f((u16)a1[1]) + b2f((u16)e1[1]);
      c.z += b2f((u16)a1[2]) + b2f((u16)e1[2]); c.w += b2f((u16)a1[3]) + b2f((u16)e1[3]);
      d.x += b2f((u16)a2[0]) + b2f((u16)e2[0]); d.y += b2f((u16)a2[1]) + b2f((u16)e2[1]);
      d.z += b2f((u16)a2[2]) + b2f((u16)e2[2]); d.w += b2f((u16)a2[3]) + b2f((u16)e2[3]);
    } else {
      const float* pf = (const float*)P;
      const float4* p0 = (const float4*)(pf + (long)xr * 768);
      const float4* p1 = (const float4*)(pf + ps + (long)xr * 768);
      float4 u0 = p0[l], u1 = p0[l + 64], u2 = p0[l + 128];
      float4 v0 = p1[l], v1 = p1[l + 64], v2 = p1[l + 128];
      a.x += u0.x + v0.x; a.y += u0.y + v0.y; a.z += u0.z + v0.z; a.w += u0.w + v0.w;
      c.x += u1.x + v1.x; c.y += u1.y + v1.y; c.z += u1.z + v1.z; c.w += u1.w + v1.w;
      d.x += u2.x + v2.x; d.y += u2.y + v2.y; d.z += u2.z + v2.z; d.w += u2.w + v2.w;
    }
  }
  if (WRITEX) {
    float4* xo = (float4*)(Xout + (long)xr * 768);
    xo[l] = a; xo[l + 64] = c; xo[l + 128] = d;
  }
  float s = a.x + a.y + a.z + a.w + c.x + c.y + c.z + c.w + d.x + d.y + d.z + d.w;
  #pragma unroll
  for (int t = 1; t < 64; t <<= 1) s += __shfl_xor(s, t);
  float mean = s * (1.f / 768.f);
  a.x -= mean; a.y -= mean; a.z -= mean; a.w -= mean;
  c.x -= mean; c.y -= mean; c.z -= mean; c.w -= mean;
  d.x -= mean; d.y -= mean; d.z -= mean; d.w -= mean;
  float q = a.x*a.x + a.y*a.y + a.z*a.z + a.w*a.w
          + c.x*c.x + c.y*c.y + c.z*c.z + c.w*c.w
          + d.x*d.x + d.y*d.y + d.z*d.z + d.w*d.w;
  #pragma unroll
  for (int t = 1; t < 64; t <<= 1) q += __shfl_xor(q, t);
  float rs = rsqrtf(q * (1.f / 768.f) + 1e-5f);
  const float4* wp = (const float4*)w;
  const float4* bp = (const float4*)bb;
  u16* out = Hb + (long)row * 768;
  float4 w0 = wp[l], w1 = wp[l + 64], w2 = wp[l + 128];
  float4 b0 = bp[l], b1 = bp[l + 64], b2 = bp[l + 128];
  short4v o;
  o[0] = (short)f2bf(a.x * rs * w0.x + b0.x); o[1] = (short)f2bf(a.y * rs * w0.y + b0.y);
  o[2] = (short)f2bf(a.z * rs * w0.z + b0.z); o[3] = (short)f2bf(a.w * rs * w0.w + b0.w);
  *(short4v*)(out + l * 4) = o;
  o[0] = (short)f2bf(c.x * rs * w1.x + b1.x); o[1] = (short)f2bf(c.y * rs * w1.y + b1.y);
  o[2] = (short)f2bf(c.z * rs * w1.z + b1.z); o[3] = (short)f2bf(c.w * rs * w1.w + b1.w);
  *(short4v*)(out + 256 + l * 4) = o;
  o[0] = (short)f2bf(d.x * rs * w2.x + b2.x); o[1] = (short)f2bf(d.y * rs * w2.y + b2.y);
  o[2] = (short)f2bf(d.z * rs * w2.z + b2.z); o[3] = (short)f2bf(d.w * rs * w2.w + b2.w);
  *(short4v*)(out + 512 + l * 4) = o;
}

// ---------------- weight transpose + f32->bf16: W[K][N] -> WT[N][K], batched over z ----------------
__global__ __launch_bounds__(256) void transpose_w(
    const float* __restrict__ W, u16* __restrict__ WT, int K, int N, long sW, long sT)
{
  __shared__ float t[64][65];
  int z = blockIdx.z;
  W += (long)z * sW; WT += (long)z * sT;
  int n0 = blockIdx.x * 64, k0 = blockIdx.y * 64;
  #pragma unroll
  for (int i = 0; i < 4; ++i) {
    int flat = i * 256 + threadIdx.x;
    int r = flat >> 4, c = (flat & 15) * 4;
    float4 v = *(const float4*)(W + (long)(k0 + r) * N + n0 + c);
    t[r][c] = v.x; t[r][c + 1] = v.y; t[r][c + 2] = v.z; t[r][c + 3] = v.w;
  }
  __syncthreads();
  #pragma unroll
  for (int i = 0; i < 8; ++i) {
    int flat = i * 256 + threadIdx.x;
    int rn = flat >> 5, ck = (flat & 31) * 2;
    unsigned val = (unsigned)f2bf(t[ck][rn]) | ((unsigned)f2bf(t[ck + 1][rn]) << 16);
    *(unsigned*)(WT + (long)(n0 + rn) * K + k0 + ck) = val;
  }
}

__global__ void convert_bf16(const float* __restrict__ src, u16* __restrict__ dst, int n4) {
  int i = blockIdx.x * 256 + threadIdx.x;
  if (i < n4) {
    float4 v = ((const float4*)src)[i];
    short4v o;
    o[0] = (short)f2bf(v.x); o[1] = (short)f2bf(v.y); o[2] = (short)f2bf(v.z); o[3] = (short)f2bf(v.w);
    *(short4v*)(dst + i * 4) = o;
  }
}

__global__ __launch_bounds__(192) void patch_extract(const float* __restrict__ img, u16* __restrict__ Xp) {
  int row = blockIdx.x;
  int t = threadIdx.x;
  int pair = t >> 2, part = t & 3;
  int cch = pair >> 4, kh = pair & 15;
  int b = row / 196, hw = row % 196, gh = hw / 14, gw = hw % 14;
  float4 v = *(const float4*)(img + ((long)(b * 3 + cch) * 224 + gh * 16 + kh) * 224 + gw * 16 + part * 4);
  short4v o;
  o[0] = (short)f2bf(v.x); o[1] = (short)f2bf(v.y); o[2] = (short)f2bf(v.z); o[3] = (short)f2bf(v.w);
  *(short4v*)(Xp + (long)row * 768 + pair * 16 + part * 4) = o;
}

__global__ void cls_pos_fill(const float* __restrict__ cls, const float* __restrict__ pos, float* __restrict__ x) {
  int i = blockIdx.x * 256 + threadIdx.x;
  if (i >= 16 * 27 * 768) return;
  int d = i % 768, t = i / 768, b = t / 27, s = t % 27;
  x[((long)b * 223 + s) * 768 + d] = cls[s * 768 + d] + pos[s * 768 + d];
}

// fused: obj = P0+P1 (head split-K partials, f32); pid = (obj/|obj|)·(sents/|sents|)
__global__ __launch_bounds__(256) void norm_dot(
    const float* __restrict__ objp, long ps, const float* __restrict__ sents,
    float* __restrict__ pid)
{
  __shared__ float sb[12];
  int r = blockIdx.x, t = threadIdx.x, b = r / 27;
  long base = (long)r * 512;
  float v0 = objp[base + t] + objp[ps + base + t];
  float v1 = objp[base + t + 256] + objp[ps + base + t + 256];
  float w0 = sents[b * 512 + t], w1 = sents[b * 512 + t + 256];
  float q = v0 * v0 + v1 * v1;
  float dt = v0 * w0 + v1 * w1;
  float sw = w0 * w0 + w1 * w1;
  #pragma unroll
  for (int d = 1; d < 64; d <<= 1) {
    q += __shfl_xor(q, d); dt += __shfl_xor(dt, d); sw += __shfl_xor(sw, d);
  }
  if ((t & 63) == 0) { sb[t >> 6] = q; sb[4 + (t >> 6)] = dt; sb[8 + (t >> 6)] = sw; }
  __syncthreads();
  if (t == 0)
    pid[r] = (sb[4] + sb[5] + sb[6] + sb[7])
           * rsqrtf(sb[0] + sb[1] + sb[2] + sb[3])
           * rsqrtf(sb[8] + sb[9] + sb[10] + sb[11]);
}

__global__ void gather_pred(const int* __restrict__ om, const float* __restrict__ pid, float* __restrict__ out) {
  int i = blockIdx.x * 256 + threadIdx.x;
  if (i >= 16 * 224 * 224) return;
  int b = i / (224 * 224);
  out[i] = pid[b * 27 + om[i]];
}

extern "C" void kernel_launch(void* const* d_in, const int* in_sizes, int n_in,
                              void* d_out, int out_size, void* d_ws, size_t ws_size,
                              hipStream_t stream) {
  const float* img     = (const float*)d_in[0];
  const float* sents   = (const float*)d_in[1];
  const int*   aom     = (const int*)d_in[2];
  const int*   omask   = (const int*)d_in[3];
  const float* cls     = (const float*)d_in[4];
  const float* patch_w = (const float*)d_in[5];
  const float* patch_b = (const float*)d_in[6];
  const float* pos     = (const float*)d_in[7];
  const float* ln1w    = (const float*)d_in[8];
  const float* ln1b    = (const float*)d_in[9];
  const float* qkvw    = (const float*)d_in[10];
  const float* qkvb    = (const float*)d_in[11];
  const float* outw    = (const float*)d_in[12];
  const float* outb    = (const float*)d_in[13];
  const float* ln2w    = (const float*)d_in[14];
  const float* ln2b    = (const float*)d_in[15];
  const float* m1w     = (const float*)d_in[16];
  const float* m1b     = (const float*)d_in[17];
  const float* m2w     = (const float*)d_in[18];
  const float* m2b     = (const float*)d_in[19];
  const float* lnpw    = (const float*)d_in[20];
  const float* lnpb    = (const float*)d_in[21];
  const float* projw   = (const float*)d_in[22];

  char* p = (char*)d_ws;
  auto alloc = [&](size_t bytes) { char* r = p; p += (bytes + 255) & ~(size_t)255; return r; };
  const long PSH = 3584l * 768;   // bf16 partial stride (elements)
  const long OPS = 432l * 512;    // head f32 partial stride
  float* x   = (float*)alloc(3568ul * 768 * 4);
  u16* H     = (u16*)alloc(3584ul * 768 * 2);
  u16* QKV   = (u16*)alloc(3584ul * 2304 * 2);
  u16* Obuf  = (u16*)alloc(3584ul * 768 * 2);
  u16* G     = (u16*)alloc(3584ul * 3072 * 2);
  u16* Yb    = (u16*)alloc((size_t)PSH * 2 * 2);  // out-proj bf16 partials (2 halves)
  u16* Mb    = (u16*)alloc((size_t)PSH * 2 * 2);  // MLP2 bf16 partials
  u16* PWc   = (u16*)alloc(768ul * 768 * 2);
  u16* PrT   = (u16*)alloc(512ul * 768 * 2);
  float* obj = (float*)alloc((size_t)OPS * 2 * 4);
  float* pid = (float*)alloc(432ul * 4);

  const size_t wlayer = (2304ul * 768 + 768ul * 768 + 3072ul * 768 + 768ul * 3072) * 2;
  size_t used = (size_t)(p - (char*)d_ws);
  int nw = (ws_size >= used + 12 * wlayer + 65536) ? 12 : 1;
  const long sQ = 2304l * 768, sO = 768l * 768, s1 = 768l * 3072, s2 = 3072l * 768;
  u16* WqT = (u16*)alloc((size_t)sQ * 2 * nw);
  u16* WoT = (u16*)alloc((size_t)sO * 2 * nw);
  u16* W1T = (u16*)alloc((size_t)s1 * 2 * nw);
  u16* W2T = (u16*)alloc((size_t)s2 * 2 * nw);

  convert_bf16<<<576, 256, 0, stream>>>(patch_w, PWc, 147456);
  transpose_w<<<dim3(8, 12, 1), 256, 0, stream>>>(projw, PrT, 768, 512, 0, 0);
  if (nw == 12) {
    transpose_w<<<dim3(36, 12, 12), 256, 0, stream>>>(qkvw, WqT, 768, 2304, sQ, sQ);
    transpose_w<<<dim3(12, 12, 12), 256, 0, stream>>>(outw, WoT, 768, 768, sO, sO);
    transpose_w<<<dim3(48, 12, 12), 256, 0, stream>>>(m1w, W1T, 768, 3072, s1, s1);
    transpose_w<<<dim3(12, 48, 12), 256, 0, stream>>>(m2w, W2T, 3072, 768, s2, s2);
  }
  patch_extract<<<3136, 192, 0, stream>>>(img, H);
  cls_pos_fill<<<1296, 256, 0, stream>>>(cls, pos, x);
  gemm_bt<64, 3, false, 1><<<dim3(12, 25), 256, 0, stream>>>(H, PWc, patch_b, x, nullptr, 3136, 768, 768, pos, 0);

  for (int l = 0; l < 12; ++l) {
    u16 *wq, *wo, *w1, *w2;
    if (nw == 12) { wq = WqT + (long)l * sQ; wo = WoT + (long)l * sO; w1 = W1T + (long)l * s1; w2 = W2T + (long)l * s2; }
    else {
      wq = WqT; wo = WoT; w1 = W1T; w2 = W2T;
      transpose_w<<<dim3(36, 12, 1), 256, 0, stream>>>(qkvw + (long)l * sQ, wq, 768, 2304, 0, 0);
      transpose_w<<<dim3(12, 12, 1), 256, 0, stream>>>(outw + (long)l * sO, wo, 768, 768, 0, 0);
      transpose_w<<<dim3(48, 12, 1), 256, 0, stream>>>(m1w + (long)l * s1, w1, 768, 3072, 0, 0);
      transpose_w<<<dim3(12, 48, 1), 256, 0, stream>>>(m2w + (long)l * s2, w2, 3072, 768, 0, 0);
    }
    if (l == 0)
      ln_kernel<0, false, false, false><<<892, 256, 0, stream>>>(x, nullptr, 0, nullptr, H, ln1w, ln1b, 3568);
    else
      ln_kernel<2, true, false, true><<<892, 256, 0, stream>>>(x, Mb, PSH, x, H, ln1w + l * 768, ln1b + l * 768, 3568);
    gemm_bt<128, 0, false, 1><<<dim3(18, 28), 256, 0, stream>>>(H, wq, qkvb + l * 2304, nullptr, QKV, 3568, 2304, 768, nullptr, 0);
    attn_kernel<<<dim3(12, 16), 512, 0, stream>>>(QKV, aom, Obuf);
    gemm_bt<64, 4, false, 2><<<dim3(12, 28, 2), 256, 0, stream>>>(Obuf, wo, outb + l * 768, nullptr, Yb, 3568, 768, 768, nullptr, PSH);
    ln_kernel<2, true, false, true><<<892, 256, 0, stream>>>(x, Yb, PSH, x, H, ln2w + l * 768, ln2b + l * 768, 3568);
    gemm_bt<128, 0, true, 1><<<dim3(24, 28), 256, 0, stream>>>(H, w1, m1b + l * 3072, nullptr, G, 3568, 3072, 768, nullptr, 0);
    gemm_bt<64, 4, false, 2><<<dim3(12, 28, 2), 256, 0, stream>>>(G, w2, m2b + l * 768, nullptr, Mb, 3568, 768, 3072, nullptr, PSH);
  }

  ln_kernel<2, true, true, false><<<108, 256, 0, stream>>>(x, Mb, PSH, nullptr, H, lnpw, lnpb, 432);
  gemm_bt<64, 2, false, 2><<<dim3(8, 4, 2), 256, 0, stream>>>(H, PrT, nullptr, obj, nullptr, 432, 512, 768, nullptr, OPS);
  norm_dot<<<432, 256, 0, stream>>>(obj, OPS, sents, pid);
  gather_pred<<<3136, 256, 0, stream>>>(omask, pid, (float*)d_out);
}

// Round 14
// 2023.146 us; speedup vs baseline: 1.1672x; 1.0105x over previous
//
#include <hip/hip_runtime.h>

#define DEV __device__ __forceinline__

typedef short bf16x8 __attribute__((ext_vector_type(8)));
typedef float f32x4 __attribute__((ext_vector_type(4)));
typedef int vi4 __attribute__((ext_vector_type(4)));
typedef unsigned uint2v __attribute__((ext_vector_type(2)));
typedef unsigned short u16;
typedef short short4v __attribute__((ext_vector_type(4)));

#define NEGV -1000000000.0f

DEV u16 f2bf(float f) {
  union { float f; unsigned u; } v; v.f = f;
  unsigned r = v.u + 0x7FFFu + ((v.u >> 16) & 1u);
  return (u16)(r >> 16);
}

DEV float b2f(u16 s) {
  union { unsigned u; float f; } v; v.u = ((unsigned)s) << 16;
  return v.f;
}

DEV bf16x8 ld_bf8(const u16* p) {
  vi4 v = *(const vi4*)p;
  return __builtin_bit_cast(bf16x8, v);
}

DEV void gload_lds16(const u16* g, vi4* l) {
  __builtin_amdgcn_global_load_lds((const __attribute__((address_space(1))) void*)g,
                                   (__attribute__((address_space(3))) void*)l, 16, 0, 0);
}

DEV unsigned lds_off(const void* p) {
  return (unsigned)(unsigned long long)(const __attribute__((address_space(3))) void*)p;
}

DEV uint2v ds_tr16(unsigned byteaddr) {
  uint2v r;
  asm volatile("ds_read_b64_tr_b16 %0, %1" : "=v"(r) : "v"(byteaddr));
  return r;
}

// ---------------- generic GEMM: C[M,N] = A[Mpad,K](bf16) @ Bt[N,K](bf16)^T ----------------
// BK=64, 2-buffer pipeline, counted vmcnt. A rows PADDED to mult of 128.
// MODE 0: Cb = bf16(acc+bias); MODE 2: Cf[+bz*pstride] = acc (+bias@z0) f32 split-K partials;
// MODE 4: Cb[+bz*pstride] = bf16(acc (+bias@z0)) bf16 split-K partials (summed by fused LN);
// MODE 3: patch-embed scatter (bf16 x) with pos_embed.
template<int BN, int MODE, bool GELU, int KS>
__global__ __launch_bounds__(256) void gemm_bt(
    const u16* __restrict__ A, const u16* __restrict__ Bt,
    const float* __restrict__ bias,
    float* __restrict__ Cf, u16* __restrict__ Cb,
    int M, int N, int K, const float* __restrict__ pos, long pstride)
{
  constexpr int FJ = BN / 32;
  constexpr int LTOT = 4 + FJ;
  __shared__ vi4 As[2][1024];
  __shared__ vi4 Bs[2][BN * 8];

  // bijective XCD-aware swizzle (m204)
  int gx = gridDim.x, gy = gridDim.y;
  int nwg = gx * gy * (int)gridDim.z;
  int orig = blockIdx.x + gx * (blockIdx.y + gy * blockIdx.z);
  int qq = nwg >> 3, rr = nwg & 7;
  int xcd = orig & 7, off = orig >> 3;
  int id = (xcd < rr) ? xcd * (qq + 1) + off : rr * (qq + 1) + (xcd - rr) * qq + off;
  int bx = id % gx, rest = id / gx, by = rest % gy, bz = rest / gy;

  int tid = threadIdx.x, lane = tid & 63, wid = tid >> 6;
  int wm = wid >> 1, wn = wid & 1;
  int m0 = by * 128, n0 = bx * BN;
  int kBeg = (K / KS) * bz;
  int nT = (K / KS) >> 6;
  f32x4 acc[4][FJ] = {};

  auto STAGE = [&](int buf, int kk) {
    #pragma unroll
    for (int r = 0; r < 4; ++r) {
      int flat = r * 256 + tid;
      int row = flat >> 3, c = flat & 7;
      int cs = c ^ (row & 7);
      gload_lds16(A + (long)(m0 + row) * K + kk + cs * 8, &As[buf][r * 256 + wid * 64]);
    }
    #pragma unroll
    for (int r = 0; r < FJ; ++r) {
      int flat = r * 256 + tid;
      int row = flat >> 3, c = flat & 7;
      int cs = c ^ (row & 7);
      gload_lds16(Bt + (long)(n0 + row) * K + kk + cs * 8, &Bs[buf][r * 256 + wid * 64]);
    }
  };

  STAGE(0, kBeg);
  int cur = 0;
  for (int t = 0; t < nT; ++t) {
    if (t + 1 < nT) {
      STAGE(cur ^ 1, kBeg + (t + 1) * 64);
      asm volatile("s_waitcnt vmcnt(%0)" :: "i"(LTOT) : "memory");
    } else {
      asm volatile("s_waitcnt vmcnt(0)" ::: "memory");
    }
    __builtin_amdgcn_s_barrier();
    int cg = lane >> 4, l15 = lane & 15;
    #pragma unroll
    for (int ks = 0; ks < 2; ++ks) {
      bf16x8 af[4], bfr[FJ];
      #pragma unroll
      for (int i = 0; i < 4; ++i) {
        int ra = wm * 64 + i * 16 + l15;
        af[i] = __builtin_bit_cast(bf16x8, As[cur][ra * 8 + ((ks * 4 + cg) ^ (ra & 7))]);
      }
      #pragma unroll
      for (int j = 0; j < FJ; ++j) {
        int rb = wn * (BN / 2) + j * 16 + l15;
        bfr[j] = __builtin_bit_cast(bf16x8, Bs[cur][rb * 8 + ((ks * 4 + cg) ^ (rb & 7))]);
      }
      #pragma unroll
      for (int i = 0; i < 4; ++i)
        #pragma unroll
        for (int j = 0; j < FJ; ++j)
          acc[i][j] = __builtin_amdgcn_mfma_f32_16x16x32_bf16(af[i], bfr[j], acc[i][j], 0, 0, 0);
    }
    __builtin_amdgcn_s_barrier();
    cur ^= 1;
  }

  int cg = lane >> 4, l15 = lane & 15;
  float* Cfz = (MODE == 2 && KS > 1) ? Cf + (long)bz * pstride : Cf;
  u16* Cbz = (MODE == 4 && KS > 1) ? Cb + (long)bz * pstride : Cb;
  #pragma unroll
  for (int i = 0; i < 4; ++i) {
    #pragma unroll
    for (int j = 0; j < FJ; ++j) {
      int col = n0 + wn * (BN / 2) + j * 16 + l15;
      float bv = bias ? bias[col] : 0.f;
      #pragma unroll
      for (int r = 0; r < 4; ++r) {
        int row = m0 + wm * 64 + i * 16 + cg * 4 + r;
        if (row < M) {
          float v = acc[i][j][r];
          if (KS == 1 || bz == 0) v += bv;
          if (GELU) v = v / (1.f + __expf(-1.702f * v));
          if (MODE == 0) Cb[(long)row * N + col] = f2bf(v);
          else if (MODE == 2) Cfz[(long)row * N + col] = v;
          else if (MODE == 4) Cbz[(long)row * N + col] = f2bf(v);
          else {
            int hw = row % 196;
            int xr = (row / 196) * 223 + 27 + hw;
            Cb[(long)xr * 768 + col] = f2bf(v + pos[(27 + hw) * 768 + col]);
          }
        }
      }
    }
  }
}

// ---------------- attention (swapped QK^T, in-register P, tr_b16 V reads) ----------------
// grid (12 heads, 16 batch); block 512 = 8 waves, each wave up to 2 q-frags of 16 rows.
// K/V/mask staged ONCE per (h,b).
__global__ __launch_bounds__(512) void attn_kernel(
    const u16* __restrict__ QKV, const int* __restrict__ aom, u16* __restrict__ O)
{
  __shared__ vi4 Kl[224 * 8];   // K row-major [key][8 chunks], chunk XOR (key&7)
  __shared__ vi4 Vl[224 * 8];   // V subtiled [sk][sd^(sk&3)][4 keys][16 d] (128B subtiles)
  __shared__ int ml[196];
  int tid = threadIdx.x, lane = tid & 63, wid = tid >> 6;  // wid 0..7
  int h = blockIdx.x, b = blockIdx.y;
  long rowbase = (long)b * 223;
  #pragma unroll
  for (int it = 0; it < 4; ++it) {
    int flat = it * 512 + tid;
    if (flat < 1792) {
      int s = flat >> 3, c = flat & 7;
      int cs = c ^ (s & 7);
      gload_lds16(QKV + (rowbase + s) * 2304 + 768 + h * 64 + cs * 8, &Kl[it * 512 + wid * 64]);
    }
  }
  #pragma unroll
  for (int it = 0; it < 4; ++it) {
    int u = it * 512 + tid;
    if (u < 1792) {
      int slin = u >> 3, inner = u & 7;
      int sk = slin >> 2, sdp = slin & 3;
      int s = sk * 4 + (inner >> 1);
      int c = ((sdp ^ (sk & 3)) << 1) | (inner & 1);
      gload_lds16(QKV + (rowbase + s) * 2304 + 1536 + h * 64 + c * 8, &Vl[it * 512 + wid * 64]);
    }
  }
  for (int i = tid; i < 196; i += 512) ml[i] = aom[b * 196 + i];

  int l15 = lane & 15, cg = lane >> 4;
  bf16x8 aq[2][2];
  #pragma unroll
  for (int rep = 0; rep < 2; ++rep) {
    int fo = wid * 2 + rep;
    int qf = (fo < 14) ? fo : 13;
    int arow = qf * 16 + l15; if (arow > 222) arow = 222;
    const u16* qb = QKV + (rowbase + arow) * 2304 + h * 64;
    aq[rep][0] = ld_bf8(qb + cg * 8);
    aq[rep][1] = ld_bf8(qb + 32 + cg * 8);
  }
  __syncthreads();

  unsigned vbase = lds_off(Vl);
  #pragma unroll
  for (int rep = 0; rep < 2; ++rep) {
    int fo = wid * 2 + rep;
    if (fo >= 14) break;
    int q0 = fo * 16;

    f32x4 sc[14];
    #pragma unroll
    for (int kf = 0; kf < 14; ++kf) {
      int key = kf * 16 + l15;
      f32x4 a = {0.f, 0.f, 0.f, 0.f};
      bf16x8 bk0 = __builtin_bit_cast(bf16x8, Kl[key * 8 + (cg ^ (key & 7))]);
      bf16x8 bk1 = __builtin_bit_cast(bf16x8, Kl[key * 8 + ((4 + cg) ^ (key & 7))]);
      a = __builtin_amdgcn_mfma_f32_16x16x32_bf16(bk0, aq[rep][0], a, 0, 0, 0);
      a = __builtin_amdgcn_mfma_f32_16x16x32_bf16(bk1, aq[rep][1], a, 0, 0, 0);
      sc[kf] = a;
    }
    int q = q0 + l15;
    float mx = -3.4e38f;
    #pragma unroll
    for (int kf = 0; kf < 14; ++kf) {
      #pragma unroll
      for (int r = 0; r < 4; ++r) {
        int key = kf * 16 + cg * 4 + r;
        float mval;
        if (key >= 223) mval = NEGV;
        else if (q >= 27) mval = (key < 27) ? NEGV : 0.f;
        else if (key < 27) mval = (key == q) ? 0.f : NEGV;
        else mval = (ml[key - 27] == q) ? 0.f : NEGV;
        float sv = sc[kf][r] * 0.125f + mval;
        sc[kf][r] = sv;
        mx = fmaxf(mx, sv);
      }
    }
    mx = fmaxf(mx, __shfl_xor(mx, 16));
    mx = fmaxf(mx, __shfl_xor(mx, 32));
    float sum = 0.f;
    #pragma unroll
    for (int kf = 0; kf < 14; ++kf) {
      #pragma unroll
      for (int r = 0; r < 4; ++r) {
        float e = __expf(sc[kf][r] - mx);
        sc[kf][r] = e; sum += e;
      }
    }
    sum += __shfl_xor(sum, 16);
    sum += __shfl_xor(sum, 32);
    float inv = 1.f / sum;
    unsigned plo[14], phi[14];
    #pragma unroll
    for (int kf = 0; kf < 14; ++kf) {
      plo[kf] = (unsigned)f2bf(sc[kf][0] * inv) | ((unsigned)f2bf(sc[kf][1] * inv) << 16);
      phi[kf] = (unsigned)f2bf(sc[kf][2] * inv) | ((unsigned)f2bf(sc[kf][3] * inv) << 16);
    }
    f32x4 oacc[4] = {};
    #pragma unroll
    for (int ks = 0; ks < 7; ++ks) {
      uint2v vr[4][2];
      int sk0 = ks * 8 + cg * 2, sk1 = sk0 + 1;
      #pragma unroll
      for (int nf = 0; nf < 4; ++nf) {
        vr[nf][0] = ds_tr16(vbase + (unsigned)(((sk0 * 4 + (nf ^ (sk0 & 3))) << 7) + l15 * 8));
        vr[nf][1] = ds_tr16(vbase + (unsigned)(((sk1 * 4 + (nf ^ (sk1 & 3))) << 7) + l15 * 8));
      }
      int src0 = ((cg & 1) << 5) + l15, src1 = src0 + 16;
      int lo0 = __shfl((int)plo[2 * ks], src0),     hi0 = __shfl((int)phi[2 * ks], src0);
      int lo1 = __shfl((int)plo[2 * ks + 1], src0), hi1 = __shfl((int)phi[2 * ks + 1], src0);
      int lo0b = __shfl((int)plo[2 * ks], src1),     hi0b = __shfl((int)phi[2 * ks], src1);
      int lo1b = __shfl((int)plo[2 * ks + 1], src1), hi1b = __shfl((int)phi[2 * ks + 1], src1);
      bool hg = (cg >> 1) & 1;
      vi4 paw = { hg ? lo1 : lo0, hg ? hi1 : hi0, hg ? lo1b : lo0b, hg ? hi1b : hi0b };
      bf16x8 pa = __builtin_bit_cast(bf16x8, paw);
      asm volatile("s_waitcnt lgkmcnt(0)" ::: "memory");
      __builtin_amdgcn_sched_barrier(0);
      #pragma unroll
      for (int nf = 0; nf < 4; ++nf) {
        vi4 bw = { (int)vr[nf][0][0], (int)vr[nf][0][1], (int)vr[nf][1][0], (int)vr[nf][1][1] };
        oacc[nf] = __builtin_amdgcn_mfma_f32_16x16x32_bf16(pa, __builtin_bit_cast(bf16x8, bw), oacc[nf], 0, 0, 0);
      }
    }
    #pragma unroll
    for (int nf = 0; nf < 4; ++nf) {
      int d = h * 64 + nf * 16 + l15;
      #pragma unroll
      for (int r = 0; r < 4; ++r) {
        int qo = q0 + cg * 4 + r;
        if (qo < 223) O[(rowbase + qo) * 768 + d] = f2bf(oacc[nf][r]);
      }
    }
  }
}

// ---------------- fused residual + LayerNorm: one WAVE per row; x is bf16 ----------------
// NADD=2: xnew = X + P0 + P1 (bf16 partials, P1 at +ps elements);
// optionally write bf16 xnew back; H = LN(xnew) using unrounded f32 values.
template<int NADD, bool MAP27, bool WRITEX>
__global__ __launch_bounds__(256) void ln_kernel(
    const u16* __restrict__ X, const u16* __restrict__ P, long ps,
    u16* __restrict__ Xout, u16* __restrict__ Hb,
    const float* __restrict__ w, const float* __restrict__ bb, int nrows)
{
  int row = blockIdx.x * 4 + (threadIdx.x >> 6);
  if (row >= nrows) return;
  int xr = MAP27 ? (row / 27) * 223 + (row % 27) : row;
  int l = threadIdx.x & 63;
  const u16* xp = X + (long)xr * 768;
  short4v xa = *(const short4v*)(xp + l * 4);
  short4v xc = *(const short4v*)(xp + 256 + l * 4);
  short4v xd = *(const short4v*)(xp + 512 + l * 4);
  float4 a = { b2f((u16)xa[0]), b2f((u16)xa[1]), b2f((u16)xa[2]), b2f((u16)xa[3]) };
  float4 c = { b2f((u16)xc[0]), b2f((u16)xc[1]), b2f((u16)xc[2]), b2f((u16)xc[3]) };
  float4 d = { b2f((u16)xd[0]), b2f((u16)xd[1]), b2f((u16)xd[2]), b2f((u16)xd[3]) };
  if (NADD == 2) {
    const u16* p0 = P + (long)xr * 768;
    const u16* p1 = P + ps + (long)xr * 768;
    short4v a0 = *(const short4v*)(p0 + l * 4);
    short4v a1 = *(const short4v*)(p0 + 256 + l * 4);
    short4v a2 = *(const short4v*)(p0 + 512 + l * 4);
    short4v e0 = *(const short4v*)(p1 + l * 4);
    short4v e1 = *(const short4v*)(p1 + 256 + l * 4);
    short4v e2 = *(const short4v*)(p1 + 512 + l * 4);
    a.x += b2f((u16)a0[0]) + b2f((u16)e0[0]); a.y += b2f((u16)a0[1]) + b2f((u16)e0[1]);
    a.z += b2f((u16)a0[2]) + b2f((u16)e0[2]); a.w += b2f((u16)a0[3]) + b2f((u16)e0[3]);
    c.x += b2f((u16)a1[0]) + b2f((u16)e1[0]); c.y += b2f((u16)a1[1]) + b2f((u16)e1[1]);
    c.z += b2f((u16)a1[2]) + b2f((u16)e1[2]); c.w += b2f((u16)a1[3]) + b2f((u16)e1[3]);
    d.x += b2f((u16)a2[0]) + b2f((u16)e2[0]); d.y += b2f((u16)a2[1]) + b2f((u16)e2[1]);
    d.z += b2f((u16)a2[2]) + b2f((u16)e2[2]); d.w += b2f((u16)a2[3]) + b2f((u16)e2[3]);
  }
  if (WRITEX) {
    u16* xo = Xout + (long)xr * 768;
    short4v o;
    o[0] = (short)f2bf(a.x); o[1] = (short)f2bf(a.y); o[2] = (short)f2bf(a.z); o[3] = (short)f2bf(a.w);
    *(short4v*)(xo + l * 4) = o;
    o[0] = (short)f2bf(c.x); o[1] = (short)f2bf(c.y); o[2] = (short)f2bf(c.z); o[3] = (short)f2bf(c.w);
    *(short4v*)(xo + 256 + l * 4) = o;
    o[0] = (short)f2bf(d.x); o[1] = (short)f2bf(d.y); o[2] = (short)f2bf(d.z); o[3] = (short)f2bf(d.w);
    *(short4v*)(xo + 512 + l * 4) = o;
  }
  float s = a.x + a.y + a.z + a.w + c.x + c.y + c.z + c.w + d.x + d.y + d.z + d.w;
  #pragma unroll
  for (int t = 1; t < 64; t <<= 1) s += __shfl_xor(s, t);
  float mean = s * (1.f / 768.f);
  a.x -= mean; a.y -= mean; a.z -= mean; a.w -= mean;
  c.x -= mean; c.y -= mean; c.z -= mean; c.w -= mean;
  d.x -= mean; d.y -= mean; d.z -= mean; d.w -= mean;
  float q = a.x*a.x + a.y*a.y + a.z*a.z + a.w*a.w
          + c.x*c.x + c.y*c.y + c.z*c.z + c.w*c.w
          + d.x*d.x + d.y*d.y + d.z*d.z + d.w*d.w;
  #pragma unroll
  for (int t = 1; t < 64; t <<= 1) q += __shfl_xor(q, t);
  float rs = rsqrtf(q * (1.f / 768.f) + 1e-5f);
  const float4* wp = (const float4*)w;
  const float4* bp = (const float4*)bb;
  u16* out = Hb + (long)row * 768;
  float4 w0 = wp[l], w1 = wp[l + 64], w2 = wp[l + 128];
  float4 b0 = bp[l], b1 = bp[l + 64], b2 = bp[l + 128];
  short4v o;
  o[0] = (short)f2bf(a.x * rs * w0.x + b0.x); o[1] = (short)f2bf(a.y * rs * w0.y + b0.y);
  o[2] = (short)f2bf(a.z * rs * w0.z + b0.z); o[3] = (short)f2bf(a.w * rs * w0.w + b0.w);
  *(short4v*)(out + l * 4) = o;
  o[0] = (short)f2bf(c.x * rs * w1.x + b1.x); o[1] = (short)f2bf(c.y * rs * w1.y + b1.y);
  o[2] = (short)f2bf(c.z * rs * w1.z + b1.z); o[3] = (short)f2bf(c.w * rs * w1.w + b1.w);
  *(short4v*)(out + 256 + l * 4) = o;
  o[0] = (short)f2bf(d.x * rs * w2.x + b2.x); o[1] = (short)f2bf(d.y * rs * w2.y + b2.y);
  o[2] = (short)f2bf(d.z * rs * w2.z + b2.z); o[3] = (short)f2bf(d.w * rs * w2.w + b2.w);
  *(short4v*)(out + 512 + l * 4) = o;
}

// ---------------- weight transpose + f32->bf16: W[K][N] -> WT[N][K], batched over z ----------------
__global__ __launch_bounds__(256) void transpose_w(
    const float* __restrict__ W, u16* __restrict__ WT, int K, int N, long sW, long sT)
{
  __shared__ float t[64][65];
  int z = blockIdx.z;
  W += (long)z * sW; WT += (long)z * sT;
  int n0 = blockIdx.x * 64, k0 = blockIdx.y * 64;
  #pragma unroll
  for (int i = 0; i < 4; ++i) {
    int flat = i * 256 + threadIdx.x;
    int r = flat >> 4, c = (flat & 15) * 4;
    float4 v = *(const float4*)(W + (long)(k0 + r) * N + n0 + c);
    t[r][c] = v.x; t[r][c + 1] = v.y; t[r][c + 2] = v.z; t[r][c + 3] = v.w;
  }
  __syncthreads();
  #pragma unroll
  for (int i = 0; i < 8; ++i) {
    int flat = i * 256 + threadIdx.x;
    int rn = flat >> 5, ck = (flat & 31) * 2;
    unsigned val = (unsigned)f2bf(t[ck][rn]) | ((unsigned)f2bf(t[ck + 1][rn]) << 16);
    *(unsigned*)(WT + (long)(n0 + rn) * K + k0 + ck) = val;
  }
}

__global__ void convert_bf16(const float* __restrict__ src, u16* __restrict__ dst, int n4) {
  int i = blockIdx.x * 256 + threadIdx.x;
  if (i < n4) {
    float4 v = ((const float4*)src)[i];
    short4v o;
    o[0] = (short)f2bf(v.x); o[1] = (short)f2bf(v.y); o[2] = (short)f2bf(v.z); o[3] = (short)f2bf(v.w);
    *(short4v*)(dst + i * 4) = o;
  }
}

__global__ __launch_bounds__(192) void patch_extract(const float* __restrict__ img, u16* __restrict__ Xp) {
  int row = blockIdx.x;
  int t = threadIdx.x;
  int pair = t >> 2, part = t & 3;
  int cch = pair >> 4, kh = pair & 15;
  int b = row / 196, hw = row % 196, gh = hw / 14, gw = hw % 14;
  float4 v = *(const float4*)(img + ((long)(b * 3 + cch) * 224 + gh * 16 + kh) * 224 + gw * 16 + part * 4);
  short4v o;
  o[0] = (short)f2bf(v.x); o[1] = (short)f2bf(v.y); o[2] = (short)f2bf(v.z); o[3] = (short)f2bf(v.w);
  *(short4v*)(Xp + (long)row * 768 + pair * 16 + part * 4) = o;
}

__global__ void cls_pos_fill(const float* __restrict__ cls, const float* __restrict__ pos, u16* __restrict__ x) {
  int i = blockIdx.x * 256 + threadIdx.x;
  if (i >= 16 * 27 * 768) return;
  int d = i % 768, t = i / 768, b = t / 27, s = t % 27;
  x[((long)b * 223 + s) * 768 + d] = f2bf(cls[s * 768 + d] + pos[s * 768 + d]);
}

// fused: obj = P0+P1 (head split-K partials, f32); pid = (obj/|obj|)·(sents/|sents|)
__global__ __launch_bounds__(256) void norm_dot(
    const float* __restrict__ objp, long ps, const float* __restrict__ sents,
    float* __restrict__ pid)
{
  __shared__ float sb[12];
  int r = blockIdx.x, t = threadIdx.x, b = r / 27;
  long base = (long)r * 512;
  float v0 = objp[base + t] + objp[ps + base + t];
  float v1 = objp[base + t + 256] + objp[ps + base + t + 256];
  float w0 = sents[b * 512 + t], w1 = sents[b * 512 + t + 256];
  float q = v0 * v0 + v1 * v1;
  float dt = v0 * w0 + v1 * w1;
  float sw = w0 * w0 + w1 * w1;
  #pragma unroll
  for (int d = 1; d < 64; d <<= 1) {
    q += __shfl_xor(q, d); dt += __shfl_xor(dt, d); sw += __shfl_xor(sw, d);
  }
  if ((t & 63) == 0) { sb[t >> 6] = q; sb[4 + (t >> 6)] = dt; sb[8 + (t >> 6)] = sw; }
  __syncthreads();
  if (t == 0)
    pid[r] = (sb[4] + sb[5] + sb[6] + sb[7])
           * rsqrtf(sb[0] + sb[1] + sb[2] + sb[3])
           * rsqrtf(sb[8] + sb[9] + sb[10] + sb[11]);
}

__global__ void gather_pred(const int* __restrict__ om, const float* __restrict__ pid, float* __restrict__ out) {
  int i = blockIdx.x * 256 + threadIdx.x;
  if (i >= 16 * 224 * 224 / 4) return;
  int b = (i * 4) / (224 * 224);
  int4 m = ((const int4*)om)[i];
  const float* pb = pid + b * 27;
  float4 o = { pb[m.x], pb[m.y], pb[m.z], pb[m.w] };
  ((float4*)out)[i] = o;
}

extern "C" void kernel_launch(void* const* d_in, const int* in_sizes, int n_in,
                              void* d_out, int out_size, void* d_ws, size_t ws_size,
                              hipStream_t stream) {
  const float* img     = (const float*)d_in[0];
  const float* sents   = (const float*)d_in[1];
  const int*   aom     = (const int*)d_in[2];
  const int*   omask   = (const int*)d_in[3];
  const float* cls     = (const float*)d_in[4];
  const float* patch_w = (const float*)d_in[5];
  const float* patch_b = (const float*)d_in[6];
  const float* pos     = (const float*)d_in[7];
  const float* ln1w    = (const float*)d_in[8];
  const float* ln1b    = (const float*)d_in[9];
  const float* qkvw    = (const float*)d_in[10];
  const float* qkvb    = (const float*)d_in[11];
  const float* outw    = (const float*)d_in[12];
  const float* outb    = (const float*)d_in[13];
  const float* ln2w    = (const float*)d_in[14];
  const float* ln2b    = (const float*)d_in[15];
  const float* m1w     = (const float*)d_in[16];
  const float* m1b     = (const float*)d_in[17];
  const float* m2w     = (const float*)d_in[18];
  const float* m2b     = (const float*)d_in[19];
  const float* lnpw    = (const float*)d_in[20];
  const float* lnpb    = (const float*)d_in[21];
  const float* projw   = (const float*)d_in[22];

  char* p = (char*)d_ws;
  auto alloc = [&](size_t bytes) { char* r = p; p += (bytes + 255) & ~(size_t)255; return r; };
  const long PSH = 3584l * 768;   // bf16 partial stride (elements)
  const long OPS = 432l * 512;    // head f32 partial stride
  u16* xb    = (u16*)alloc(3568ul * 768 * 2);
  u16* H     = (u16*)alloc(3584ul * 768 * 2);
  u16* QKV   = (u16*)alloc(3584ul * 2304 * 2);
  u16* Obuf  = (u16*)alloc(3584ul * 768 * 2);
  u16* G     = (u16*)alloc(3584ul * 3072 * 2);
  u16* Yb    = (u16*)alloc((size_t)PSH * 2 * 2);  // out-proj bf16 partials (2 halves)
  u16* Mb    = (u16*)alloc((size_t)PSH * 2 * 2);  // MLP2 bf16 partials
  u16* PWc   = (u16*)alloc(768ul * 768 * 2);
  u16* PrT   = (u16*)alloc(512ul * 768 * 2);
  float* obj = (float*)alloc((size_t)OPS * 2 * 4);
  float* pid = (float*)alloc(432ul * 4);

  const size_t wlayer = (2304ul * 768 + 768ul * 768 + 3072ul * 768 + 768ul * 3072) * 2;
  size_t used = (size_t)(p - (char*)d_ws);
  int nw = (ws_size >= used + 12 * wlayer + 65536) ? 12 : 1;
  const long sQ = 2304l * 768, sO = 768l * 768, s1 = 768l * 3072, s2 = 3072l * 768;
  u16* WqT = (u16*)alloc((size_t)sQ * 2 * nw);
  u16* WoT = (u16*)alloc((size_t)sO * 2 * nw);
  u16* W1T = (u16*)alloc((size_t)s1 * 2 * nw);
  u16* W2T = (u16*)alloc((size_t)s2 * 2 * nw);

  convert_bf16<<<576, 256, 0, stream>>>(patch_w, PWc, 147456);
  transpose_w<<<dim3(8, 12, 1), 256, 0, stream>>>(projw, PrT, 768, 512, 0, 0);
  if (nw == 12) {
    transpose_w<<<dim3(36, 12, 12), 256, 0, stream>>>(qkvw, WqT, 768, 2304, sQ, sQ);
    transpose_w<<<dim3(12, 12, 12), 256, 0, stream>>>(outw, WoT, 768, 768, sO, sO);
    transpose_w<<<dim3(48, 12, 12), 256, 0, stream>>>(m1w, W1T, 768, 3072, s1, s1);
    transpose_w<<<dim3(12, 48, 12), 256, 0, stream>>>(m2w, W2T, 3072, 768, s2, s2);
  }
  patch_extract<<<3136, 192, 0, stream>>>(img, H);
  cls_pos_fill<<<1296, 256, 0, stream>>>(cls, pos, xb);
  gemm_bt<64, 3, false, 1><<<dim3(12, 25), 256, 0, stream>>>(H, PWc, patch_b, nullptr, xb, 3136, 768, 768, pos, 0);

  for (int l = 0; l < 12; ++l) {
    u16 *wq, *wo, *w1, *w2;
    if (nw == 12) { wq = WqT + (long)l * sQ; wo = WoT + (long)l * sO; w1 = W1T + (long)l * s1; w2 = W2T + (long)l * s2; }
    else {
      wq = WqT; wo = WoT; w1 = W1T; w2 = W2T;
      transpose_w<<<dim3(36, 12, 1), 256, 0, stream>>>(qkvw + (long)l * sQ, wq, 768, 2304, 0, 0);
      transpose_w<<<dim3(12, 12, 1), 256, 0, stream>>>(outw + (long)l * sO, wo, 768, 768, 0, 0);
      transpose_w<<<dim3(48, 12, 1), 256, 0, stream>>>(m1w + (long)l * s1, w1, 768, 3072, 0, 0);
      transpose_w<<<dim3(12, 48, 1), 256, 0, stream>>>(m2w + (long)l * s2, w2, 3072, 768, 0, 0);
    }
    if (l == 0)
      ln_kernel<0, false, false><<<892, 256, 0, stream>>>(xb, nullptr, 0, nullptr, H, ln1w, ln1b, 3568);
    else
      ln_kernel<2, false, true><<<892, 256, 0, stream>>>(xb, Mb, PSH, xb, H, ln1w + l * 768, ln1b + l * 768, 3568);
    gemm_bt<128, 0, false, 1><<<dim3(18, 28), 256, 0, stream>>>(H, wq, qkvb + l * 2304, nullptr, QKV, 3568, 2304, 768, nullptr, 0);
    attn_kernel<<<dim3(12, 16), 512, 0, stream>>>(QKV, aom, Obuf);
    gemm_bt<64, 4, false, 2><<<dim3(12, 28, 2), 256, 0, stream>>>(Obuf, wo, outb + l * 768, nullptr, Yb, 3568, 768, 768, nullptr, PSH);
    ln_kernel<2, false, true><<<892, 256, 0, stream>>>(xb, Yb, PSH, xb, H, ln2w + l * 768, ln2b + l * 768, 3568);
    gemm_bt<128, 0, true, 1><<<dim3(24, 28), 256, 0, stream>>>(H, w1, m1b + l * 3072, nullptr, G, 3568, 3072, 768, nullptr, 0);
    gemm_bt<64, 4, false, 2><<<dim3(12, 28, 2), 256, 0, stream>>>(G, w2, m2b + l * 768, nullptr, Mb, 3568, 768, 3072, nullptr, PSH);
  }

  ln_kernel<2, true, false><<<108, 256, 0, stream>>>(xb, Mb, PSH, nullptr, H, lnpw, lnpb, 432);
  gemm_bt<64, 2, false, 2><<<dim3(8, 4, 2), 256, 0, stream>>>(H, PrT, nullptr, obj, nullptr, 432, 512, 768, nullptr, OPS);
  norm_dot<<<432, 256, 0, stream>>>(obj, OPS, sents, pid);
  gather_pred<<<784, 256, 0, stream>>>(omask, pid, (float*)d_out);
}